// Round 8
// baseline (470.988 us; speedup 1.0000x reference)
//
#include <hip/hip_runtime.h>
#include <stdint.h>
#include <stddef.h>
#include <float.h>

typedef short bf16x8 __attribute__((ext_vector_type(8)));
typedef float f32x4 __attribute__((ext_vector_type(4)));

// ---------------- helpers ----------------
static __device__ __forceinline__ unsigned enc_min(float v) {
  unsigned u = __float_as_uint(v);
  return (u & 0x80000000u) ? ~u : (u | 0x80000000u);
}
static __device__ __forceinline__ unsigned short f2bf(float f) {
  unsigned u = __float_as_uint(f);
  u += 0x7fffu + ((u >> 16) & 1u);
  return (unsigned short)(u >> 16);
}
static __device__ __forceinline__ float bf2f(unsigned short b) {
  return __uint_as_float(((unsigned)b) << 16);
}
static __device__ __forceinline__ void acc8(float* a, uint4 v) {
  a[0] += __uint_as_float(v.x << 16);
  a[1] += __uint_as_float(v.x & 0xffff0000u);
  a[2] += __uint_as_float(v.y << 16);
  a[3] += __uint_as_float(v.y & 0xffff0000u);
  a[4] += __uint_as_float(v.z << 16);
  a[5] += __uint_as_float(v.z & 0xffff0000u);
  a[6] += __uint_as_float(v.w << 16);
  a[7] += __uint_as_float(v.w & 0xffff0000u);
}

// ---------------- count + bin: ONE streaming pass over edges ----------------
// Degree counts are FIRE-AND-FORGET atomics (no return value -> no fabric
// round-trip on the critical path; R6's rank-returning version stalled each
// tile on its slowest atomic: 78.8us at 1.6% VALU). Rank/CSR-slot assignment
// moves to the scatter (hidden under GEMM1). Pairs = plain (dst, src) into 8
// dst-range buckets via block-aggregated reservation (1 global atomic per bin
// per 1024-edge tile).
__global__ __launch_bounds__(256) void k_count_bin(const int* __restrict__ edge, int E, int N,
                                                   int* __restrict__ cnt8,
                                                   int* __restrict__ bin_cur,
                                                   int2* __restrict__ pairs,
                                                   int binw, int bcap) {
  __shared__ int h[8], gbase[8], lfill[8];
  int* cnt = cnt8 + (size_t)(blockIdx.x & 7) * N;
  int tid = threadIdx.x;
  int nt = (E + 1023) >> 10;
  for (int t = blockIdx.x; t < nt; t += gridDim.x) {
    int e0 = t << 10;
    if (tid < 8) { h[tid] = 0; lfill[tid] = 0; }
    __syncthreads();
    int d[4], s[4], g[4];
#pragma unroll
    for (int k = 0; k < 4; ++k) {
      int e = e0 + tid + k * 256;
      d[k] = -1;
      if (e < E) {
        d[k] = edge[E + e];
        s[k] = edge[e];
        g[k] = (int)((unsigned)d[k] / (unsigned)binw);
        atomicAdd(&cnt[d[k]], 1);   // fire-and-forget: no return dependency
        atomicAdd(&h[g[k]], 1);
      }
    }
    __syncthreads();
    if (tid < 8) gbase[tid] = atomicAdd(&bin_cur[tid], h[tid]);
    __syncthreads();
#pragma unroll
    for (int k = 0; k < 4; ++k) {
      if (d[k] >= 0) {
        int rr = atomicAdd(&lfill[g[k]], 1);
        int p = gbase[g[k]] + rr;
        if (p < bcap) pairs[(size_t)g[k] * bcap + p] = make_int2(d[k], s[k]);
      }
    }
    __syncthreads();  // protect h/lfill reuse next tile
  }
}

// ---------------- block inclusive scan (1024/block) + 8-way cnt reduce ----------------
__global__ void k_scan1(const int* __restrict__ cnt8, int N,
                        int* __restrict__ cnt, int* __restrict__ incl,
                        int* __restrict__ bsum) {
  __shared__ int sm[1024];
  int tid = threadIdx.x;
  int i = blockIdx.x * 1024 + tid;
  int v = 0;
  if (i < N) {
#pragma unroll
    for (int g = 0; g < 8; ++g) v += cnt8[(size_t)g * N + i];
    cnt[i] = v;  // summed degree for k_aux
  }
  sm[tid] = v;
  __syncthreads();
  for (int off = 1; off < 1024; off <<= 1) {
    int t = (tid >= off) ? sm[tid - off] : 0;
    __syncthreads();
    sm[tid] += t;
    __syncthreads();
  }
  if (i < N) incl[i] = sm[tid];
  if (tid == 1023) bsum[blockIdx.x] = sm[1023];
}

// ---------------- scan of block sums (nb <= 128) ----------------
__global__ void k_scan2(const int* __restrict__ bsum, int nb, int* __restrict__ boff) {
  __shared__ int sm[128];
  int tid = threadIdx.x;
  int v = (tid < nb) ? bsum[tid] : 0;
  sm[tid] = v;
  __syncthreads();
  for (int off = 1; off < 128; off <<= 1) {
    int t = (tid >= off) ? sm[tid - off] : 0;
    __syncthreads();
    sm[tid] += t;
    __syncthreads();
  }
  if (tid < nb) boff[tid] = sm[tid] - v;  // exclusive
}

// ---------------- row_ptr / cursor / dinv ----------------
__global__ void k_aux(const int* __restrict__ cnt, const int* __restrict__ incl,
                      const int* __restrict__ boff, int N, int E,
                      int* __restrict__ row_ptr, int* __restrict__ cursor,
                      float* __restrict__ dinv) {
  int i = blockIdx.x * blockDim.x + threadIdx.x;
  if (i < N) {
    int rp = incl[i] - cnt[i] + boff[i >> 10];
    row_ptr[i] = rp;
    cursor[i] = rp;
    dinv[i] = 1.0f / sqrtf((float)(cnt[i] + 1));  // +1 self-loop
  } else if (i == N) {
    row_ptr[N] = E;
  }
}

// ---------------- weight prep: W[k][n] fp32 -> lane-ordered bf16 hi/lo fragments -----
__global__ void k_prepw(const float* __restrict__ W1, const float* __restrict__ W2,
                        const float* __restrict__ W3,
                        unsigned short* __restrict__ w1h, unsigned short* __restrict__ w1l,
                        unsigned short* __restrict__ w2h, unsigned short* __restrict__ w2l,
                        unsigned short* __restrict__ w3h, unsigned short* __restrict__ w3l) {
  const int K = 128;
  int idx = blockIdx.x * 256 + threadIdx.x;
  const float* W;
  unsigned short *oh, *ol;
  int Nn, base;
  if (idx < 16384) { W = W1; Nn = 128; oh = w1h; ol = w1l; base = idx; }
  else if (idx < 32768) { W = W2; Nn = 128; oh = w2h; ol = w2l; base = idx - 16384; }
  else if (idx < 40960) { W = W3; Nn = 64; oh = w3h; ol = w3l; base = idx - 32768; }
  else return;
  int n = base / K, k = base % K;
  float w = W[(size_t)k * Nn + n];
  unsigned short h = f2bf(w);
  unsigned short l = f2bf(w - bf2f(h));
  int nf = n >> 4, mloc = n & 15, kci = k >> 5, quad = (k >> 3) & 3, j = k & 7;
  size_t o = ((size_t)((nf * 4 + kci) * 64 + quad * 16 + mloc)) * 8 + j;
  oh[o] = h;
  ol[o] = l;
}

// ---------------- GEMM device body: fp32 A rows -> contiguous bf16 rows (dinv-scaled)
template <int NFW>
static __device__ __forceinline__ void gemm_body(const float* __restrict__ A,
                                                 const unsigned short* __restrict__ Wfh,
                                                 const unsigned short* __restrict__ Wfl,
                                                 const float* __restrict__ dinv,
                                                 unsigned short* __restrict__ P, int M,
                                                 int blk) {
  const int K = 128;
  const int COUT = NFW * 64;
  __shared__ unsigned short Ah[64][136];
  __shared__ unsigned short Al[64][136];
  int tid = threadIdx.x;
  int m0 = blk * 64;
  int w = tid >> 6, lane = tid & 63;

  bf16x8 bh[NFW][4], bl[NFW][4];
#pragma unroll
  for (int i = 0; i < NFW; ++i)
#pragma unroll
    for (int kci = 0; kci < 4; ++kci) {
      size_t o = ((size_t)(((w * NFW + i) * 4 + kci) * 64 + lane)) * 8;
      bh[i][kci] = *(const bf16x8*)&Wfh[o];
      bl[i][kci] = *(const bf16x8*)&Wfl[o];
    }

#pragma unroll
  for (int q = 0; q < 8; ++q) {
    int f = q * 256 + tid;
    int m = f >> 5, k4 = f & 31;
    int row = m0 + m;
    if (row >= M) row = M - 1;
    float4 v = *(const float4*)&A[(size_t)row * K + k4 * 4];
    unsigned short h0 = f2bf(v.x), h1 = f2bf(v.y), h2 = f2bf(v.z), h3 = f2bf(v.w);
    unsigned short l0 = f2bf(v.x - bf2f(h0)), l1 = f2bf(v.y - bf2f(h1));
    unsigned short l2 = f2bf(v.z - bf2f(h2)), l3 = f2bf(v.w - bf2f(h3));
    uint2 hh, ll;
    hh.x = (unsigned)h0 | ((unsigned)h1 << 16);
    hh.y = (unsigned)h2 | ((unsigned)h3 << 16);
    ll.x = (unsigned)l0 | ((unsigned)l1 << 16);
    ll.y = (unsigned)l2 | ((unsigned)l3 << 16);
    *(uint2*)&Ah[m][k4 * 4] = hh;
    *(uint2*)&Al[m][k4 * 4] = ll;
  }
  __syncthreads();

  int mloc = lane & 15, quad = lane >> 4;
  f32x4 acc[4][NFW];
#pragma unroll
  for (int rt = 0; rt < 4; ++rt)
#pragma unroll
    for (int i = 0; i < NFW; ++i) acc[rt][i] = (f32x4){0.f, 0.f, 0.f, 0.f};

#pragma unroll
  for (int rt = 0; rt < 4; ++rt) {
    const unsigned short* ph = &Ah[rt * 16 + mloc][quad * 8];
    const unsigned short* pl = &Al[rt * 16 + mloc][quad * 8];
#pragma unroll
    for (int kci = 0; kci < 4; ++kci) {
      bf16x8 ah = *(const bf16x8*)(ph + kci * 32);
      bf16x8 al = *(const bf16x8*)(pl + kci * 32);
#pragma unroll
      for (int i = 0; i < NFW; ++i) {
        acc[rt][i] = __builtin_amdgcn_mfma_f32_16x16x32_bf16(al, bh[i][kci], acc[rt][i], 0, 0, 0);
        acc[rt][i] = __builtin_amdgcn_mfma_f32_16x16x32_bf16(ah, bl[i][kci], acc[rt][i], 0, 0, 0);
        acc[rt][i] = __builtin_amdgcn_mfma_f32_16x16x32_bf16(ah, bh[i][kci], acc[rt][i], 0, 0, 0);
      }
    }
  }

#pragma unroll
  for (int rt = 0; rt < 4; ++rt) {
    int rbase = m0 + rt * 16 + quad * 4;
#pragma unroll
    for (int r = 0; r < 4; ++r) {
      int row = rbase + r;
      if (row < M) {
        float dv = dinv[row];
#pragma unroll
        for (int i = 0; i < NFW; ++i) {
          int nf = w * NFW + i;
          P[(size_t)row * COUT + nf * 16 + mloc] = f2bf(acc[rt][i][r] * dv);
        }
      }
    }
  }
}

// ---------------- FUSED: cursor-atomic scatter (blocks < ns) + layer-1 GEMM ---------
// Scatter is latency-bound (atomicAdd-with-return + dependent store) but rides
// in the GEMM family's shadow; 4-deep unroll overlaps four fabric round-trips
// per thread. Order within a dst is nondeterministic (was already, via rank
// timing) -- aggregation is a sum, so this only permutes fp addition order.
__global__ __launch_bounds__(256) void k_fill_gemm(const float* __restrict__ A,
                                                   const unsigned short* __restrict__ Wfh,
                                                   const unsigned short* __restrict__ Wfl,
                                                   const float* __restrict__ dinv,
                                                   unsigned short* __restrict__ P, int M,
                                                   const int2* __restrict__ pairs,
                                                   const int* __restrict__ bin_cur, int bcap,
                                                   int* __restrict__ cursor,
                                                   int* __restrict__ srcs, int ns) {
  if ((int)blockIdx.x >= ns) {
    gemm_body<2>(A, Wfh, Wfl, dinv, P, M, blockIdx.x - ns);
  } else {
    int grp = blockIdx.x & 7;
    int bslot = blockIdx.x >> 3;
    int nslot = ns >> 3;
    int cnt_g = bin_cur[grp];
    if (cnt_g > bcap) cnt_g = bcap;
    const int2* pp = pairs + (size_t)grp * bcap;
    int stride = nslot * (int)blockDim.x;
    int i = bslot * (int)blockDim.x + (int)threadIdx.x;
    for (; i + 3 * stride < cnt_g; i += 4 * stride) {
      int2 p0 = pp[i];
      int2 p1 = pp[i + stride];
      int2 p2 = pp[i + 2 * stride];
      int2 p3 = pp[i + 3 * stride];
      int o0 = atomicAdd(&cursor[p0.x], 1);
      int o1 = atomicAdd(&cursor[p1.x], 1);
      int o2 = atomicAdd(&cursor[p2.x], 1);
      int o3 = atomicAdd(&cursor[p3.x], 1);
      srcs[o0] = p0.y;
      srcs[o1] = p1.y;
      srcs[o2] = p2.y;
      srcs[o3] = p3.y;
    }
    for (; i < cnt_g; i += stride) {
      int2 p0 = pp[i];
      srcs[atomicAdd(&cursor[p0.x], 1)] = p0.y;
    }
  }
}

// ---------------- FUSED per-layer: gather (8-deep MLP) -> H tile -> MFMA -> Pout -----
// Block = 16 dsts, 16 lanes/dst (16B of the 256B pre-scaled bf16 row). 8-deep
// unrolled gather; rows are dinv-pre-scaled so exactly ONE dependent load/edge.
template <int NFW>  // output channels = NFW*64
__global__ __launch_bounds__(256) void k_agg_gemm(const unsigned short* __restrict__ Pin,
                                                  const int* __restrict__ row_ptr,
                                                  const int* __restrict__ srcs,
                                                  const float* __restrict__ dinv,
                                                  const float* __restrict__ bias,
                                                  const unsigned short* __restrict__ Wfh,
                                                  const unsigned short* __restrict__ Wfl,
                                                  unsigned short* __restrict__ Pout, int N) {
  const int COUT = NFW * 64;
  __shared__ unsigned short Ah[16][136];
  __shared__ unsigned short Al[16][136];
  int tid = threadIdx.x;
  int wv = tid >> 6, lane = tid & 63;
  int grp = lane >> 4, sub = lane & 15;
  int m = wv * 4 + grp;                 // row in 16-row tile
  int d = blockIdx.x * 16 + m;
  int dc = d < N ? d : N - 1;
  bool valid = d < N;
  unsigned soff = (unsigned)sub * 16u;  // byte offset in 256B row
  const char* Pb = (const char*)Pin;

  float a[8] = {0.f, 0.f, 0.f, 0.f, 0.f, 0.f, 0.f, 0.f};
  {  // self-loop contribution = own row
    uint4 v = *(const uint4*)(Pb + ((unsigned)dc * 256u + soff));
    acc8(a, v);
  }
  int lo = row_ptr[dc];
  int hi = row_ptr[valid ? d + 1 : dc];
  int j = lo;
  for (; j + 8 <= hi; j += 8) {
    unsigned id[8];
    uint4 vv[8];
#pragma unroll
    for (int k = 0; k < 8; ++k) id[k] = (unsigned)srcs[j + k];
#pragma unroll
    for (int k = 0; k < 8; ++k) vv[k] = *(const uint4*)(Pb + (id[k] * 256u + soff));
#pragma unroll
    for (int k = 0; k < 8; ++k) acc8(a, vv[k]);
  }
  for (; j + 4 <= hi; j += 4) {
    unsigned id[4];
    uint4 vv[4];
#pragma unroll
    for (int k = 0; k < 4; ++k) id[k] = (unsigned)srcs[j + k];
#pragma unroll
    for (int k = 0; k < 4; ++k) vv[k] = *(const uint4*)(Pb + (id[k] * 256u + soff));
#pragma unroll
    for (int k = 0; k < 4; ++k) acc8(a, vv[k]);
  }
  for (; j < hi; ++j) {
    unsigned i0 = (unsigned)srcs[j];
    uint4 v0 = *(const uint4*)(Pb + (i0 * 256u + soff));
    acc8(a, v0);
  }

  // weight fragments (issued here: overlap with epilogue VALU + barrier)
  bf16x8 bh[NFW][4], bl[NFW][4];
#pragma unroll
  for (int i = 0; i < NFW; ++i)
#pragma unroll
    for (int kci = 0; kci < 4; ++kci) {
      size_t o = ((size_t)(((wv * NFW + i) * 4 + kci) * 64 + lane)) * 8;
      bh[i][kci] = *(const bf16x8*)&Wfh[o];
      bl[i][kci] = *(const bf16x8*)&Wfl[o];
    }

  // H = relu(dinv*agg + bias) -> bf16 hi/lo -> LDS
  float dv = dinv[dc];
  int ch0 = sub * 8;
  float4 bv0 = *(const float4*)&bias[ch0];
  float4 bv1 = *(const float4*)&bias[ch0 + 4];
  float h[8];
  h[0] = dv * a[0] + bv0.x; h[1] = dv * a[1] + bv0.y;
  h[2] = dv * a[2] + bv0.z; h[3] = dv * a[3] + bv0.w;
  h[4] = dv * a[4] + bv1.x; h[5] = dv * a[5] + bv1.y;
  h[6] = dv * a[6] + bv1.z; h[7] = dv * a[7] + bv1.w;
#pragma unroll
  for (int k = 0; k < 8; ++k) h[k] = fmaxf(h[k], 0.f);
  unsigned short hb[8], lb[8];
#pragma unroll
  for (int k = 0; k < 8; ++k) {
    hb[k] = f2bf(h[k]);
    lb[k] = f2bf(h[k] - bf2f(hb[k]));
  }
  uint4 HH, LL;
  HH.x = (unsigned)hb[0] | ((unsigned)hb[1] << 16);
  HH.y = (unsigned)hb[2] | ((unsigned)hb[3] << 16);
  HH.z = (unsigned)hb[4] | ((unsigned)hb[5] << 16);
  HH.w = (unsigned)hb[6] | ((unsigned)hb[7] << 16);
  LL.x = (unsigned)lb[0] | ((unsigned)lb[1] << 16);
  LL.y = (unsigned)lb[2] | ((unsigned)lb[3] << 16);
  LL.z = (unsigned)lb[4] | ((unsigned)lb[5] << 16);
  LL.w = (unsigned)lb[6] | ((unsigned)lb[7] << 16);
  *(uint4*)&Ah[m][ch0] = HH;
  *(uint4*)&Al[m][ch0] = LL;
  __syncthreads();

  // MFMA: 16 rows x COUT, K=128 -> Pout rows scaled by dinv[row]
  int mloc = lane & 15, quad = lane >> 4;
  f32x4 acc[NFW];
#pragma unroll
  for (int i = 0; i < NFW; ++i) acc[i] = (f32x4){0.f, 0.f, 0.f, 0.f};
#pragma unroll
  for (int kci = 0; kci < 4; ++kci) {
    bf16x8 ah = *(const bf16x8*)&Ah[mloc][quad * 8 + kci * 32];
    bf16x8 al = *(const bf16x8*)&Al[mloc][quad * 8 + kci * 32];
#pragma unroll
    for (int i = 0; i < NFW; ++i) {
      acc[i] = __builtin_amdgcn_mfma_f32_16x16x32_bf16(al, bh[i][kci], acc[i], 0, 0, 0);
      acc[i] = __builtin_amdgcn_mfma_f32_16x16x32_bf16(ah, bl[i][kci], acc[i], 0, 0, 0);
      acc[i] = __builtin_amdgcn_mfma_f32_16x16x32_bf16(ah, bh[i][kci], acc[i], 0, 0, 0);
    }
  }
  int rbase = blockIdx.x * 16 + quad * 4;
#pragma unroll
  for (int r = 0; r < 4; ++r) {
    int row = rbase + r;
    if (row < N) {
      float dvr = dinv[row];
#pragma unroll
      for (int i = 0; i < NFW; ++i) {
        int nf = wv * NFW + i;
        Pout[(size_t)row * COUT + nf * 16 + mloc] = f2bf(acc[i][r] * dvr);
      }
    }
  }
}

// ---------------- final layer: R3-style sliced staged aggregation + min-pool --------
// 2 slices x 4 parts per 256-dst chunk; srcs indices staged once per 16-dst
// wave window into LDS (read once from global per wave, reused by 64 lanes).
__global__ __launch_bounds__(256) void k_agg_pool(const unsigned short* __restrict__ P,
                                                  const int* __restrict__ row_ptr,
                                                  const int* __restrict__ srcs,
                                                  const float* __restrict__ dinv,
                                                  const float* __restrict__ bias,
                                                  unsigned* __restrict__ minenc, int N) {
  const int CAP = 448;
  __shared__ int s_idx[4][CAP];
  __shared__ float s_red[4][32];
  int tid = threadIdx.x;
  int wv = tid >> 6, lane = tid & 63;
  int b8 = blockIdx.x & 7;
  int slice = b8 >> 2, part = b8 & 3;  // 2 slices x 4 parts
  int g0 = ((blockIdx.x >> 3) * 4 + part) * 64 + wv * 16;
  const char* Pb = (const char*)P + slice * 64;  // rows are 128B contiguous

  int i = lane >> 2, q = lane & 3;
  unsigned qoff = (unsigned)q * 16u;
  int d = g0 + i;
  int dc = d < N ? d : N - 1;
  bool valid = d < N;

  int e0 = row_ptr[g0 < N ? g0 : N];
  int e1 = row_ptr[(g0 + 16) < N ? (g0 + 16) : N];
  int lo_n = row_ptr[dc];
  int hi_n = row_ptr[valid ? d + 1 : dc];

  float a[8];
  {
    uint4 v = *(const uint4*)(Pb + ((unsigned)dc * 128u + qoff));
    a[0] = __uint_as_float(v.x << 16);
    a[1] = __uint_as_float(v.x & 0xffff0000u);
    a[2] = __uint_as_float(v.y << 16);
    a[3] = __uint_as_float(v.y & 0xffff0000u);
    a[4] = __uint_as_float(v.z << 16);
    a[5] = __uint_as_float(v.z & 0xffff0000u);
    a[6] = __uint_as_float(v.w << 16);
    a[7] = __uint_as_float(v.w & 0xffff0000u);
  }

  for (int w0 = e0; w0 < e1; w0 += CAP) {
    int wend = min(w0 + CAP, e1);
    int cnt = wend - w0;
    __builtin_amdgcn_wave_barrier();
    for (int t = lane; t < cnt; t += 64) s_idx[wv][t] = srcs[w0 + t];
    __builtin_amdgcn_wave_barrier();
    int j = max(lo_n, w0), hi = min(hi_n, wend);
    for (; j + 4 <= hi; j += 4) {
      unsigned i0 = (unsigned)s_idx[wv][j - w0];
      unsigned i1 = (unsigned)s_idx[wv][j - w0 + 1];
      unsigned i2 = (unsigned)s_idx[wv][j - w0 + 2];
      unsigned i3 = (unsigned)s_idx[wv][j - w0 + 3];
      uint4 v0 = *(const uint4*)(Pb + (i0 * 128u + qoff));
      uint4 v1 = *(const uint4*)(Pb + (i1 * 128u + qoff));
      uint4 v2 = *(const uint4*)(Pb + (i2 * 128u + qoff));
      uint4 v3 = *(const uint4*)(Pb + (i3 * 128u + qoff));
      acc8(a, v0);
      acc8(a, v1);
      acc8(a, v2);
      acc8(a, v3);
    }
    for (; j < hi; ++j) {
      unsigned i0 = (unsigned)s_idx[wv][j - w0];
      uint4 v0 = *(const uint4*)(Pb + (i0 * 128u + qoff));
      acc8(a, v0);
    }
  }

  int c0 = slice * 32 + q * 8;
  float dv = dinv[dc];
  float4 bv0 = *(const float4*)&bias[c0];
  float4 bv1 = *(const float4*)&bias[c0 + 4];
  float h[8];
  h[0] = dv * a[0] + bv0.x; h[1] = dv * a[1] + bv0.y;
  h[2] = dv * a[2] + bv0.z; h[3] = dv * a[3] + bv0.w;
  h[4] = dv * a[4] + bv1.x; h[5] = dv * a[5] + bv1.y;
  h[6] = dv * a[6] + bv1.z; h[7] = dv * a[7] + bv1.w;

  if (!valid) {
#pragma unroll
    for (int k = 0; k < 8; ++k) h[k] = FLT_MAX;
  }
#pragma unroll
  for (int off = 4; off < 64; off <<= 1) {
#pragma unroll
    for (int k = 0; k < 8; ++k) h[k] = fminf(h[k], __shfl_xor(h[k], off, 64));
  }
  if (lane < 4) {
#pragma unroll
    for (int k = 0; k < 8; ++k) s_red[wv][q * 8 + k] = h[k];
  }
  __syncthreads();
  if (tid < 32) {
    float mn = fminf(fminf(s_red[0][tid], s_red[1][tid]),
                     fminf(s_red[2][tid], s_red[3][tid]));
    atomicMin(&minenc[slice * 32 + tid], enc_min(mn));
  }
}

__global__ void k_decode(const unsigned* __restrict__ minenc, float* __restrict__ out) {
  int c = threadIdx.x;
  unsigned k = minenc[c];
  unsigned u = (k & 0x80000000u) ? (k & 0x7FFFFFFFu) : ~k;
  out[c] = __uint_as_float(u);
}

// ---------------- launch ----------------
extern "C" void kernel_launch(void* const* d_in, const int* in_sizes, int n_in,
                              void* d_out, int out_size, void* d_ws, size_t ws_size,
                              hipStream_t stream) {
  const float* X  = (const float*)d_in[0];
  const int* edge = (const int*)d_in[1];
  const float* W1 = (const float*)d_in[2];
  const float* b1 = (const float*)d_in[3];
  const float* W2 = (const float*)d_in[4];
  const float* b2 = (const float*)d_in[5];
  const float* W3 = (const float*)d_in[6];
  const float* b3 = (const float*)d_in[7];
  float* out = (float*)d_out;

  const int IN_CH = 128;
  int N = in_sizes[0] / IN_CH;
  int E = in_sizes[1] / 2;

  char* ws = (char*)d_ws;
  size_t off = 0;
  auto alloc = [&](size_t bytes) {
    void* p = ws + off;
    off = (off + bytes + 255) & ~(size_t)255;
    return p;
  };
  unsigned short* P1 = (unsigned short*)alloc((size_t)N * 128 * 2);  // 25.6 MB, 256B rows
  unsigned short* P2 = (unsigned short*)alloc((size_t)N * 128 * 2);  // 25.6 MB
  int* srcs      = (int*)alloc((size_t)E * 4);                       // 6.4 MB
  int* cnt8      = (int*)alloc((size_t)8 * N * 4);                   // 3.2 MB private copies
  int* cnt       = (int*)alloc((size_t)N * 4);
  int* incl      = (int*)alloc((size_t)N * 4);
  int* row_ptr   = (int*)alloc((size_t)(N + 1) * 4);
  int* cursor    = (int*)alloc((size_t)N * 4);
  float* dinv    = (float*)alloc((size_t)N * 4);
  int* bsum      = (int*)alloc(1024);
  int* boff      = (int*)alloc(1024);
  int* bin_cur   = (int*)alloc(256);
  unsigned* minenc = (unsigned*)alloc(256);
  unsigned short* w1h = (unsigned short*)alloc(16384 * 2);
  unsigned short* w1l = (unsigned short*)alloc(16384 * 2);
  unsigned short* w2h = (unsigned short*)alloc(16384 * 2);
  unsigned short* w2l = (unsigned short*)alloc(16384 * 2);
  unsigned short* w3h = (unsigned short*)alloc(8192 * 2);
  unsigned short* w3l = (unsigned short*)alloc(8192 * 2);

  // Aliases (lifetime-checked):
  //  pairs -> P2 region: written by k_count_bin, consumed by k_fill_gemm's scatter,
  //           both strictly before k_agg_gemm<2> writes P2.
  //  P3    -> P1 region: P1 last read by k_agg_gemm<2>; k_agg_gemm<1> reads P2
  //           and writes P3.
  int bcap = E / 8 + 65536;
  int binw = (N + 7) / 8;
  int2* pairs = (int2*)P2;                   // 8*bcap*8B = 17.1 MB <= 25.6 MB
  unsigned short* P3 = P1;

  hipMemsetAsync(cnt8, 0, (size_t)8 * N * 4, stream);
  hipMemsetAsync(bin_cur, 0, 32, stream);
  hipMemsetAsync(minenc, 0xFF, 64 * 4, stream);  // encoded +max

  int nb = (N + 1023) / 1024;
  int gx = (N + 63) / 64;
  int ns = 1024;  // scatter blocks (multiple of 8)
  int gagg = (N + 15) / 16;
  int c64 = (N + 255) / 256;
  k_prepw<<<160, 256, 0, stream>>>(W1, W2, W3, w1h, w1l, w2h, w2l, w3h, w3l);
  k_count_bin<<<782, 256, 0, stream>>>(edge, E, N, cnt8, bin_cur, pairs, binw, bcap);
  k_scan1<<<nb, 1024, 0, stream>>>(cnt8, N, cnt, incl, bsum);
  k_scan2<<<1, 128, 0, stream>>>(bsum, nb, boff);
  k_aux<<<(N + 256) / 256, 256, 0, stream>>>(cnt, incl, boff, N, E, row_ptr, cursor, dinv);

  // layer 1: fused cursor-atomic scatter (first ns blocks) + gemm1 (X*W1 -> P1)
  k_fill_gemm<<<ns + gx, 256, 0, stream>>>(X, w1h, w1l, dinv, P1, N,
                                           pairs, bin_cur, bcap, cursor, srcs, ns);
  // layer 1 agg + layer 2 gemm fused: P1 -> (H1) -> P2
  k_agg_gemm<2><<<gagg, 256, 0, stream>>>(P1, row_ptr, srcs, dinv, b1, w2h, w2l, P2, N);
  // layer 2 agg + layer 3 gemm fused: P2 -> (H2) -> P3
  k_agg_gemm<1><<<gagg, 256, 0, stream>>>(P2, row_ptr, srcs, dinv, b2, w3h, w3l, P3, N);
  // layer 3 agg + bias + min-pool (R3 staged variant)
  k_agg_pool<<<c64 * 8, 256, 0, stream>>>(P3, row_ptr, srcs, dinv, b3, minenc, N);
  // decode encoded mins -> out[64]
  k_decode<<<1, 64, 0, stream>>>(minenc, out);
}

// Round 9
// 420.586 us; speedup vs baseline: 1.1198x; 1.1198x over previous
//
#include <hip/hip_runtime.h>
#include <stdint.h>
#include <stddef.h>
#include <float.h>

typedef short bf16x8 __attribute__((ext_vector_type(8)));
typedef float f32x4 __attribute__((ext_vector_type(4)));

// ---------------- helpers ----------------
static __device__ __forceinline__ unsigned enc_min(float v) {
  unsigned u = __float_as_uint(v);
  return (u & 0x80000000u) ? ~u : (u | 0x80000000u);
}
static __device__ __forceinline__ unsigned short f2bf(float f) {
  unsigned u = __float_as_uint(f);
  u += 0x7fffu + ((u >> 16) & 1u);
  return (unsigned short)(u >> 16);
}
static __device__ __forceinline__ float bf2f(unsigned short b) {
  return __uint_as_float(((unsigned)b) << 16);
}
static __device__ __forceinline__ void acc8(float* a, uint4 v) {
  a[0] += __uint_as_float(v.x << 16);
  a[1] += __uint_as_float(v.x & 0xffff0000u);
  a[2] += __uint_as_float(v.y << 16);
  a[3] += __uint_as_float(v.y & 0xffff0000u);
  a[4] += __uint_as_float(v.z << 16);
  a[5] += __uint_as_float(v.z & 0xffff0000u);
  a[6] += __uint_as_float(v.w << 16);
  a[7] += __uint_as_float(v.w & 0xffff0000u);
}

// ---------------- count + bin: ONE pass over edges (R3-verified) ----------------
// Degree counts into XCD-private copies; rank r = atomicAdd return + copy slot
// packed into the pair word -> the later CSR scatter is a pure store
// (slot = base8[c][d] + r), atomic-free. Counting atomics are paid HERE, once,
// in the kernel that must touch every edge anyway (R7/R8 falsified both
// "fire-and-forget" and "move atomics to scatter" alternatives).
__global__ __launch_bounds__(256) void k_count_bin(const int* __restrict__ edge, int E, int N,
                                                   int* __restrict__ cnt8,
                                                   int* __restrict__ bin_cur,
                                                   int2* __restrict__ pairs,
                                                   int binw, int bcap) {
  __shared__ int h[8], gbase[8], lfill[8];
  int cslot = blockIdx.x & 7;
  int* cnt = cnt8 + (size_t)cslot * N;
  int tid = threadIdx.x;
  int nt = (E + 1023) >> 10;
  for (int t = blockIdx.x; t < nt; t += gridDim.x) {
    int e0 = t << 10;
    if (tid < 8) { h[tid] = 0; lfill[tid] = 0; }
    __syncthreads();
    int d[4], s[4], g[4], r[4];
#pragma unroll
    for (int k = 0; k < 4; ++k) {
      int e = e0 + tid + k * 256;
      d[k] = -1;
      if (e < E) {
        d[k] = edge[E + e];
        s[k] = edge[e];
        g[k] = (int)((unsigned)d[k] / (unsigned)binw);
        r[k] = atomicAdd(&cnt[d[k]], 1);
        atomicAdd(&h[g[k]], 1);
      }
    }
    __syncthreads();
    if (tid < 8) gbase[tid] = atomicAdd(&bin_cur[tid], h[tid]);
    __syncthreads();
#pragma unroll
    for (int k = 0; k < 4; ++k) {
      if (d[k] >= 0) {
        int rr = atomicAdd(&lfill[g[k]], 1);
        int p = gbase[g[k]] + rr;
        unsigned packed = (unsigned)d[k] | ((unsigned)cslot << 17) | ((unsigned)r[k] << 20);
        if (p < bcap) pairs[(size_t)g[k] * bcap + p] = make_int2((int)packed, s[k]);
      }
    }
    __syncthreads();  // protect h/lfill reuse next tile
  }
}

// ---------------- block inclusive scan (1024/block) + 8-way cnt reduce ----------------
__global__ void k_scan1(const int* __restrict__ cnt8, int N,
                        int* __restrict__ cnt, int* __restrict__ incl,
                        int* __restrict__ bsum) {
  __shared__ int sm[1024];
  int tid = threadIdx.x;
  int i = blockIdx.x * 1024 + tid;
  int v = 0;
  if (i < N) {
#pragma unroll
    for (int g = 0; g < 8; ++g) v += cnt8[(size_t)g * N + i];
    cnt[i] = v;  // summed degree for k_aux
  }
  sm[tid] = v;
  __syncthreads();
  for (int off = 1; off < 1024; off <<= 1) {
    int t = (tid >= off) ? sm[tid - off] : 0;
    __syncthreads();
    sm[tid] += t;
    __syncthreads();
  }
  if (i < N) incl[i] = sm[tid];
  if (tid == 1023) bsum[blockIdx.x] = sm[1023];
}

// ---------------- scan of block sums (nb <= 128) ----------------
__global__ void k_scan2(const int* __restrict__ bsum, int nb, int* __restrict__ boff) {
  __shared__ int sm[128];
  int tid = threadIdx.x;
  int v = (tid < nb) ? bsum[tid] : 0;
  sm[tid] = v;
  __syncthreads();
  for (int off = 1; off < 128; off <<= 1) {
    int t = (tid >= off) ? sm[tid - off] : 0;
    __syncthreads();
    sm[tid] += t;
    __syncthreads();
  }
  if (tid < nb) boff[tid] = sm[tid] - v;  // exclusive
}

// ---------------- row_ptr / per-copy scatter bases / dinv ----------------
__global__ void k_aux(const int* __restrict__ cnt, const int* __restrict__ cnt8,
                      const int* __restrict__ incl, const int* __restrict__ boff,
                      int N, int E, int* __restrict__ row_ptr,
                      int* __restrict__ base8, float* __restrict__ dinv) {
  int i = blockIdx.x * blockDim.x + threadIdx.x;
  if (i < N) {
    int rp = incl[i] - cnt[i] + boff[i >> 10];
    row_ptr[i] = rp;
    dinv[i] = 1.0f / sqrtf((float)(cnt[i] + 1));  // +1 self-loop
    int run = rp;
#pragma unroll
    for (int c = 0; c < 8; ++c) {
      base8[(size_t)c * N + i] = run;
      run += cnt8[(size_t)c * N + i];
    }
  } else if (i == N) {
    row_ptr[N] = E;
  }
}

// ---------------- weight prep: W[k][n] fp32 -> lane-ordered bf16 hi/lo fragments -----
__global__ void k_prepw(const float* __restrict__ W1, const float* __restrict__ W2,
                        const float* __restrict__ W3,
                        unsigned short* __restrict__ w1h, unsigned short* __restrict__ w1l,
                        unsigned short* __restrict__ w2h, unsigned short* __restrict__ w2l,
                        unsigned short* __restrict__ w3h, unsigned short* __restrict__ w3l) {
  const int K = 128;
  int idx = blockIdx.x * 256 + threadIdx.x;
  const float* W;
  unsigned short *oh, *ol;
  int Nn, base;
  if (idx < 16384) { W = W1; Nn = 128; oh = w1h; ol = w1l; base = idx; }
  else if (idx < 32768) { W = W2; Nn = 128; oh = w2h; ol = w2l; base = idx - 16384; }
  else if (idx < 40960) { W = W3; Nn = 64; oh = w3h; ol = w3l; base = idx - 32768; }
  else return;
  int n = base / K, k = base % K;
  float w = W[(size_t)k * Nn + n];
  unsigned short h = f2bf(w);
  unsigned short l = f2bf(w - bf2f(h));
  int nf = n >> 4, mloc = n & 15, kci = k >> 5, quad = (k >> 3) & 3, j = k & 7;
  size_t o = ((size_t)((nf * 4 + kci) * 64 + quad * 16 + mloc)) * 8 + j;
  oh[o] = h;
  ol[o] = l;
}

// ---------------- GEMM device body: fp32 A rows -> contiguous bf16 rows (dinv-scaled)
template <int NFW>
static __device__ __forceinline__ void gemm_body(const float* __restrict__ A,
                                                 const unsigned short* __restrict__ Wfh,
                                                 const unsigned short* __restrict__ Wfl,
                                                 const float* __restrict__ dinv,
                                                 unsigned short* __restrict__ P, int M,
                                                 int blk) {
  const int K = 128;
  const int COUT = NFW * 64;
  __shared__ unsigned short Ah[64][136];
  __shared__ unsigned short Al[64][136];
  int tid = threadIdx.x;
  int m0 = blk * 64;
  int w = tid >> 6, lane = tid & 63;

  bf16x8 bh[NFW][4], bl[NFW][4];
#pragma unroll
  for (int i = 0; i < NFW; ++i)
#pragma unroll
    for (int kci = 0; kci < 4; ++kci) {
      size_t o = ((size_t)(((w * NFW + i) * 4 + kci) * 64 + lane)) * 8;
      bh[i][kci] = *(const bf16x8*)&Wfh[o];
      bl[i][kci] = *(const bf16x8*)&Wfl[o];
    }

#pragma unroll
  for (int q = 0; q < 8; ++q) {
    int f = q * 256 + tid;
    int m = f >> 5, k4 = f & 31;
    int row = m0 + m;
    if (row >= M) row = M - 1;
    float4 v = *(const float4*)&A[(size_t)row * K + k4 * 4];
    unsigned short h0 = f2bf(v.x), h1 = f2bf(v.y), h2 = f2bf(v.z), h3 = f2bf(v.w);
    unsigned short l0 = f2bf(v.x - bf2f(h0)), l1 = f2bf(v.y - bf2f(h1));
    unsigned short l2 = f2bf(v.z - bf2f(h2)), l3 = f2bf(v.w - bf2f(h3));
    uint2 hh, ll;
    hh.x = (unsigned)h0 | ((unsigned)h1 << 16);
    hh.y = (unsigned)h2 | ((unsigned)h3 << 16);
    ll.x = (unsigned)l0 | ((unsigned)l1 << 16);
    ll.y = (unsigned)l2 | ((unsigned)l3 << 16);
    *(uint2*)&Ah[m][k4 * 4] = hh;
    *(uint2*)&Al[m][k4 * 4] = ll;
  }
  __syncthreads();

  int mloc = lane & 15, quad = lane >> 4;
  f32x4 acc[4][NFW];
#pragma unroll
  for (int rt = 0; rt < 4; ++rt)
#pragma unroll
    for (int i = 0; i < NFW; ++i) acc[rt][i] = (f32x4){0.f, 0.f, 0.f, 0.f};

#pragma unroll
  for (int rt = 0; rt < 4; ++rt) {
    const unsigned short* ph = &Ah[rt * 16 + mloc][quad * 8];
    const unsigned short* pl = &Al[rt * 16 + mloc][quad * 8];
#pragma unroll
    for (int kci = 0; kci < 4; ++kci) {
      bf16x8 ah = *(const bf16x8*)(ph + kci * 32);
      bf16x8 al = *(const bf16x8*)(pl + kci * 32);
#pragma unroll
      for (int i = 0; i < NFW; ++i) {
        acc[rt][i] = __builtin_amdgcn_mfma_f32_16x16x32_bf16(al, bh[i][kci], acc[rt][i], 0, 0, 0);
        acc[rt][i] = __builtin_amdgcn_mfma_f32_16x16x32_bf16(ah, bl[i][kci], acc[rt][i], 0, 0, 0);
        acc[rt][i] = __builtin_amdgcn_mfma_f32_16x16x32_bf16(ah, bh[i][kci], acc[rt][i], 0, 0, 0);
      }
    }
  }

#pragma unroll
  for (int rt = 0; rt < 4; ++rt) {
    int rbase = m0 + rt * 16 + quad * 4;
#pragma unroll
    for (int r = 0; r < 4; ++r) {
      int row = rbase + r;
      if (row < M) {
        float dv = dinv[row];
#pragma unroll
        for (int i = 0; i < NFW; ++i) {
          int nf = w * NFW + i;
          P[(size_t)row * COUT + nf * 16 + mloc] = f2bf(acc[rt][i][r] * dv);
        }
      }
    }
  }
}

// ---------------- FUSED: atomic-free bucket scatter (blocks < ns) + layer-1 GEMM ----
// Scatter blocks launch FIRST so they drain inside the GEMM's shadow. Each
// reads only its own bucket's packed pairs and stores srcs[base8[c][d]+r]
// -- no atomics, no dependent chains, fully pipelineable (R3-verified <=77us).
__global__ __launch_bounds__(256) void k_fill_gemm(const float* __restrict__ A,
                                                   const unsigned short* __restrict__ Wfh,
                                                   const unsigned short* __restrict__ Wfl,
                                                   const float* __restrict__ dinv,
                                                   unsigned short* __restrict__ P, int M,
                                                   const int2* __restrict__ pairs,
                                                   const int* __restrict__ bin_cur, int bcap,
                                                   const int* __restrict__ base8, int N,
                                                   int* __restrict__ srcs, int ns) {
  if ((int)blockIdx.x >= ns) {
    gemm_body<2>(A, Wfh, Wfl, dinv, P, M, blockIdx.x - ns);
  } else {
    int grp = blockIdx.x & 7;
    int bslot = blockIdx.x >> 3;
    int nslot = ns >> 3;
    int cnt_g = bin_cur[grp];
    if (cnt_g > bcap) cnt_g = bcap;
    const int2* pp = pairs + (size_t)grp * bcap;
    for (int i = bslot * blockDim.x + threadIdx.x; i < cnt_g; i += nslot * blockDim.x) {
      int2 pr = pp[i];
      unsigned w = (unsigned)pr.x;
      int d = (int)(w & 0x1FFFFu);
      int c = (int)((w >> 17) & 7u);
      int r = (int)(w >> 20);
      srcs[base8[(size_t)c * N + d] + r] = pr.y;
    }
  }
}

// ---------------- FUSED per-layer: gather (8-deep MLP) -> H tile -> MFMA -> Pout -----
// Block = 16 dsts, 16 lanes/dst (16B of the 256B pre-scaled bf16 row). 8-deep
// unrolled gather (counter-verified R6: 80.5->77.2us, FETCH invariant);
// rows are dinv-pre-scaled so exactly ONE dependent load per edge.
template <int NFW>  // output channels = NFW*64
__global__ __launch_bounds__(256) void k_agg_gemm(const unsigned short* __restrict__ Pin,
                                                  const int* __restrict__ row_ptr,
                                                  const int* __restrict__ srcs,
                                                  const float* __restrict__ dinv,
                                                  const float* __restrict__ bias,
                                                  const unsigned short* __restrict__ Wfh,
                                                  const unsigned short* __restrict__ Wfl,
                                                  unsigned short* __restrict__ Pout, int N) {
  const int COUT = NFW * 64;
  __shared__ unsigned short Ah[16][136];
  __shared__ unsigned short Al[16][136];
  int tid = threadIdx.x;
  int wv = tid >> 6, lane = tid & 63;
  int grp = lane >> 4, sub = lane & 15;
  int m = wv * 4 + grp;                 // row in 16-row tile
  int d = blockIdx.x * 16 + m;
  int dc = d < N ? d : N - 1;
  bool valid = d < N;
  unsigned soff = (unsigned)sub * 16u;  // byte offset in 256B row
  const char* Pb = (const char*)Pin;

  float a[8] = {0.f, 0.f, 0.f, 0.f, 0.f, 0.f, 0.f, 0.f};
  {  // self-loop contribution = own row
    uint4 v = *(const uint4*)(Pb + ((unsigned)dc * 256u + soff));
    acc8(a, v);
  }
  int lo = row_ptr[dc];
  int hi = row_ptr[valid ? d + 1 : dc];
  int j = lo;
  for (; j + 8 <= hi; j += 8) {
    unsigned id[8];
    uint4 vv[8];
#pragma unroll
    for (int k = 0; k < 8; ++k) id[k] = (unsigned)srcs[j + k];
#pragma unroll
    for (int k = 0; k < 8; ++k) vv[k] = *(const uint4*)(Pb + (id[k] * 256u + soff));
#pragma unroll
    for (int k = 0; k < 8; ++k) acc8(a, vv[k]);
  }
  for (; j + 4 <= hi; j += 4) {
    unsigned id[4];
    uint4 vv[4];
#pragma unroll
    for (int k = 0; k < 4; ++k) id[k] = (unsigned)srcs[j + k];
#pragma unroll
    for (int k = 0; k < 4; ++k) vv[k] = *(const uint4*)(Pb + (id[k] * 256u + soff));
#pragma unroll
    for (int k = 0; k < 4; ++k) acc8(a, vv[k]);
  }
  for (; j < hi; ++j) {
    unsigned i0 = (unsigned)srcs[j];
    uint4 v0 = *(const uint4*)(Pb + (i0 * 256u + soff));
    acc8(a, v0);
  }

  // weight fragments (issued here: overlap with epilogue VALU + barrier)
  bf16x8 bh[NFW][4], bl[NFW][4];
#pragma unroll
  for (int i = 0; i < NFW; ++i)
#pragma unroll
    for (int kci = 0; kci < 4; ++kci) {
      size_t o = ((size_t)(((wv * NFW + i) * 4 + kci) * 64 + lane)) * 8;
      bh[i][kci] = *(const bf16x8*)&Wfh[o];
      bl[i][kci] = *(const bf16x8*)&Wfl[o];
    }

  // H = relu(dinv*agg + bias) -> bf16 hi/lo -> LDS
  float dv = dinv[dc];
  int ch0 = sub * 8;
  float4 bv0 = *(const float4*)&bias[ch0];
  float4 bv1 = *(const float4*)&bias[ch0 + 4];
  float h[8];
  h[0] = dv * a[0] + bv0.x; h[1] = dv * a[1] + bv0.y;
  h[2] = dv * a[2] + bv0.z; h[3] = dv * a[3] + bv0.w;
  h[4] = dv * a[4] + bv1.x; h[5] = dv * a[5] + bv1.y;
  h[6] = dv * a[6] + bv1.z; h[7] = dv * a[7] + bv1.w;
#pragma unroll
  for (int k = 0; k < 8; ++k) h[k] = fmaxf(h[k], 0.f);
  unsigned short hb[8], lb[8];
#pragma unroll
  for (int k = 0; k < 8; ++k) {
    hb[k] = f2bf(h[k]);
    lb[k] = f2bf(h[k] - bf2f(hb[k]));
  }
  uint4 HH, LL;
  HH.x = (unsigned)hb[0] | ((unsigned)hb[1] << 16);
  HH.y = (unsigned)hb[2] | ((unsigned)hb[3] << 16);
  HH.z = (unsigned)hb[4] | ((unsigned)hb[5] << 16);
  HH.w = (unsigned)hb[6] | ((unsigned)hb[7] << 16);
  LL.x = (unsigned)lb[0] | ((unsigned)lb[1] << 16);
  LL.y = (unsigned)lb[2] | ((unsigned)lb[3] << 16);
  LL.z = (unsigned)lb[4] | ((unsigned)lb[5] << 16);
  LL.w = (unsigned)lb[6] | ((unsigned)lb[7] << 16);
  *(uint4*)&Ah[m][ch0] = HH;
  *(uint4*)&Al[m][ch0] = LL;
  __syncthreads();

  // MFMA: 16 rows x COUT, K=128 -> Pout rows scaled by dinv[row]
  int mloc = lane & 15, quad = lane >> 4;
  f32x4 acc[NFW];
#pragma unroll
  for (int i = 0; i < NFW; ++i) acc[i] = (f32x4){0.f, 0.f, 0.f, 0.f};
#pragma unroll
  for (int kci = 0; kci < 4; ++kci) {
    bf16x8 ah = *(const bf16x8*)&Ah[mloc][quad * 8 + kci * 32];
    bf16x8 al = *(const bf16x8*)&Al[mloc][quad * 8 + kci * 32];
#pragma unroll
    for (int i = 0; i < NFW; ++i) {
      acc[i] = __builtin_amdgcn_mfma_f32_16x16x32_bf16(al, bh[i][kci], acc[i], 0, 0, 0);
      acc[i] = __builtin_amdgcn_mfma_f32_16x16x32_bf16(ah, bl[i][kci], acc[i], 0, 0, 0);
      acc[i] = __builtin_amdgcn_mfma_f32_16x16x32_bf16(ah, bh[i][kci], acc[i], 0, 0, 0);
    }
  }
  int rbase = blockIdx.x * 16 + quad * 4;
#pragma unroll
  for (int r = 0; r < 4; ++r) {
    int row = rbase + r;
    if (row < N) {
      float dvr = dinv[row];
#pragma unroll
      for (int i = 0; i < NFW; ++i) {
        int nf = wv * NFW + i;
        Pout[(size_t)row * COUT + nf * 16 + mloc] = f2bf(acc[i][r] * dvr);
      }
    }
  }
}

// ---------------- final layer: R3-verified sliced staged aggregation + min-pool -----
// 2 slices x 4 parts per 256-dst chunk; srcs indices staged ONCE per 16-dst
// wave window into LDS (vs direct gather's 8x redundant index reads -- R6's
// direct variant cost ~+18us).
__global__ __launch_bounds__(256) void k_agg_pool(const unsigned short* __restrict__ P,
                                                  const int* __restrict__ row_ptr,
                                                  const int* __restrict__ srcs,
                                                  const float* __restrict__ dinv,
                                                  const float* __restrict__ bias,
                                                  unsigned* __restrict__ minenc, int N) {
  const int CAP = 448;
  __shared__ int s_idx[4][CAP];
  __shared__ float s_red[4][32];
  int tid = threadIdx.x;
  int wv = tid >> 6, lane = tid & 63;
  int b8 = blockIdx.x & 7;
  int slice = b8 >> 2, part = b8 & 3;  // 2 slices x 4 parts
  int g0 = ((blockIdx.x >> 3) * 4 + part) * 64 + wv * 16;
  const char* Pb = (const char*)P + slice * 64;  // rows are 128B contiguous

  int i = lane >> 2, q = lane & 3;
  unsigned qoff = (unsigned)q * 16u;
  int d = g0 + i;
  int dc = d < N ? d : N - 1;
  bool valid = d < N;

  int e0 = row_ptr[g0 < N ? g0 : N];
  int e1 = row_ptr[(g0 + 16) < N ? (g0 + 16) : N];
  int lo_n = row_ptr[dc];
  int hi_n = row_ptr[valid ? d + 1 : dc];

  float a[8];
  {
    uint4 v = *(const uint4*)(Pb + ((unsigned)dc * 128u + qoff));
    a[0] = __uint_as_float(v.x << 16);
    a[1] = __uint_as_float(v.x & 0xffff0000u);
    a[2] = __uint_as_float(v.y << 16);
    a[3] = __uint_as_float(v.y & 0xffff0000u);
    a[4] = __uint_as_float(v.z << 16);
    a[5] = __uint_as_float(v.z & 0xffff0000u);
    a[6] = __uint_as_float(v.w << 16);
    a[7] = __uint_as_float(v.w & 0xffff0000u);
  }

  for (int w0 = e0; w0 < e1; w0 += CAP) {
    int wend = min(w0 + CAP, e1);
    int cnt = wend - w0;
    __builtin_amdgcn_wave_barrier();
    for (int t = lane; t < cnt; t += 64) s_idx[wv][t] = srcs[w0 + t];
    __builtin_amdgcn_wave_barrier();
    int j = max(lo_n, w0), hi = min(hi_n, wend);
    for (; j + 4 <= hi; j += 4) {
      unsigned i0 = (unsigned)s_idx[wv][j - w0];
      unsigned i1 = (unsigned)s_idx[wv][j - w0 + 1];
      unsigned i2 = (unsigned)s_idx[wv][j - w0 + 2];
      unsigned i3 = (unsigned)s_idx[wv][j - w0 + 3];
      uint4 v0 = *(const uint4*)(Pb + (i0 * 128u + qoff));
      uint4 v1 = *(const uint4*)(Pb + (i1 * 128u + qoff));
      uint4 v2 = *(const uint4*)(Pb + (i2 * 128u + qoff));
      uint4 v3 = *(const uint4*)(Pb + (i3 * 128u + qoff));
      acc8(a, v0);
      acc8(a, v1);
      acc8(a, v2);
      acc8(a, v3);
    }
    for (; j < hi; ++j) {
      unsigned i0 = (unsigned)s_idx[wv][j - w0];
      uint4 v0 = *(const uint4*)(Pb + (i0 * 128u + qoff));
      acc8(a, v0);
    }
  }

  int c0 = slice * 32 + q * 8;
  float dv = dinv[dc];
  float4 bv0 = *(const float4*)&bias[c0];
  float4 bv1 = *(const float4*)&bias[c0 + 4];
  float h[8];
  h[0] = dv * a[0] + bv0.x; h[1] = dv * a[1] + bv0.y;
  h[2] = dv * a[2] + bv0.z; h[3] = dv * a[3] + bv0.w;
  h[4] = dv * a[4] + bv1.x; h[5] = dv * a[5] + bv1.y;
  h[6] = dv * a[6] + bv1.z; h[7] = dv * a[7] + bv1.w;

  if (!valid) {
#pragma unroll
    for (int k = 0; k < 8; ++k) h[k] = FLT_MAX;
  }
#pragma unroll
  for (int off = 4; off < 64; off <<= 1) {
#pragma unroll
    for (int k = 0; k < 8; ++k) h[k] = fminf(h[k], __shfl_xor(h[k], off, 64));
  }
  if (lane < 4) {
#pragma unroll
    for (int k = 0; k < 8; ++k) s_red[wv][q * 8 + k] = h[k];
  }
  __syncthreads();
  if (tid < 32) {
    float mn = fminf(fminf(s_red[0][tid], s_red[1][tid]),
                     fminf(s_red[2][tid], s_red[3][tid]));
    atomicMin(&minenc[slice * 32 + tid], enc_min(mn));
  }
}

__global__ void k_decode(const unsigned* __restrict__ minenc, float* __restrict__ out) {
  int c = threadIdx.x;
  unsigned k = minenc[c];
  unsigned u = (k & 0x80000000u) ? (k & 0x7FFFFFFFu) : ~k;
  out[c] = __uint_as_float(u);
}

// ---------------- launch ----------------
extern "C" void kernel_launch(void* const* d_in, const int* in_sizes, int n_in,
                              void* d_out, int out_size, void* d_ws, size_t ws_size,
                              hipStream_t stream) {
  const float* X  = (const float*)d_in[0];
  const int* edge = (const int*)d_in[1];
  const float* W1 = (const float*)d_in[2];
  const float* b1 = (const float*)d_in[3];
  const float* W2 = (const float*)d_in[4];
  const float* b2 = (const float*)d_in[5];
  const float* W3 = (const float*)d_in[6];
  const float* b3 = (const float*)d_in[7];
  float* out = (float*)d_out;

  const int IN_CH = 128;
  int N = in_sizes[0] / IN_CH;
  int E = in_sizes[1] / 2;

  char* ws = (char*)d_ws;
  size_t off = 0;
  auto alloc = [&](size_t bytes) {
    void* p = ws + off;
    off = (off + bytes + 255) & ~(size_t)255;
    return p;
  };
  unsigned short* P1 = (unsigned short*)alloc((size_t)N * 128 * 2);  // 25.6 MB, 256B rows
  unsigned short* P2 = (unsigned short*)alloc((size_t)N * 128 * 2);  // 25.6 MB
  int* srcs      = (int*)alloc((size_t)E * 4);                       // 6.4 MB
  int* cnt8      = (int*)alloc((size_t)8 * N * 4);                   // 3.2 MB private copies
  int* base8     = (int*)alloc((size_t)8 * N * 4);                   // 3.2 MB scatter bases
  int* cnt       = (int*)alloc((size_t)N * 4);
  int* incl      = (int*)alloc((size_t)N * 4);
  int* row_ptr   = (int*)alloc((size_t)(N + 1) * 4);
  float* dinv    = (float*)alloc((size_t)N * 4);
  int* bsum      = (int*)alloc(1024);
  int* boff      = (int*)alloc(1024);
  int* bin_cur   = (int*)alloc(256);
  unsigned* minenc = (unsigned*)alloc(256);
  unsigned short* w1h = (unsigned short*)alloc(16384 * 2);
  unsigned short* w1l = (unsigned short*)alloc(16384 * 2);
  unsigned short* w2h = (unsigned short*)alloc(16384 * 2);
  unsigned short* w2l = (unsigned short*)alloc(16384 * 2);
  unsigned short* w3h = (unsigned short*)alloc(8192 * 2);
  unsigned short* w3l = (unsigned short*)alloc(8192 * 2);

  // Aliases (lifetime-checked):
  //  pairs -> P2 region: written by k_count_bin, consumed by k_fill_gemm's scatter,
  //           both strictly before k_agg_gemm<2> writes P2.
  //  P3    -> P1 region: P1 last read by k_agg_gemm<2>; k_agg_gemm<1> reads P2
  //           and writes P3.
  int bcap = E / 8 + 65536;
  int binw = (N + 7) / 8;
  int2* pairs = (int2*)P2;                   // 8*bcap*8B = 17.1 MB <= 25.6 MB
  unsigned short* P3 = P1;

  hipMemsetAsync(cnt8, 0, (size_t)8 * N * 4, stream);
  hipMemsetAsync(bin_cur, 0, 32, stream);
  hipMemsetAsync(minenc, 0xFF, 64 * 4, stream);  // encoded +max

  int nb = (N + 1023) / 1024;
  int gx = (N + 63) / 64;
  int ns = 1024;  // scatter blocks (multiple of 8)
  int gagg = (N + 15) / 16;
  int c64 = (N + 255) / 256;
  k_prepw<<<160, 256, 0, stream>>>(W1, W2, W3, w1h, w1l, w2h, w2l, w3h, w3l);
  k_count_bin<<<782, 256, 0, stream>>>(edge, E, N, cnt8, bin_cur, pairs, binw, bcap);
  k_scan1<<<nb, 1024, 0, stream>>>(cnt8, N, cnt, incl, bsum);
  k_scan2<<<1, 128, 0, stream>>>(bsum, nb, boff);
  k_aux<<<(N + 256) / 256, 256, 0, stream>>>(cnt, cnt8, incl, boff, N, E, row_ptr, base8, dinv);

  // layer 1: fused atomic-free scatter (first ns blocks) + gemm1 (X*W1 -> P1)
  k_fill_gemm<<<ns + gx, 256, 0, stream>>>(X, w1h, w1l, dinv, P1, N,
                                           pairs, bin_cur, bcap, base8, N, srcs, ns);
  // layer 1 agg + layer 2 gemm fused: P1 -> (H1) -> P2
  k_agg_gemm<2><<<gagg, 256, 0, stream>>>(P1, row_ptr, srcs, dinv, b1, w2h, w2l, P2, N);
  // layer 2 agg + layer 3 gemm fused: P2 -> (H2) -> P3
  k_agg_gemm<1><<<gagg, 256, 0, stream>>>(P2, row_ptr, srcs, dinv, b2, w3h, w3l, P3, N);
  // layer 3 agg + bias + min-pool (R3 staged variant)
  k_agg_pool<<<c64 * 8, 256, 0, stream>>>(P3, row_ptr, srcs, dinv, b3, minenc, N);
  // decode encoded mins -> out[64]
  k_decode<<<1, 64, 0, stream>>>(minenc, out);
}

// Round 10
// 362.651 us; speedup vs baseline: 1.2987x; 1.1598x over previous
//
#include <hip/hip_runtime.h>
#include <stdint.h>
#include <stddef.h>
#include <float.h>

typedef short bf16x8 __attribute__((ext_vector_type(8)));
typedef float f32x4 __attribute__((ext_vector_type(4)));

#define NB 256  // dst-range buckets; binw = ceil(N/256) = 391 @ N=100K -> LDS counters fit

// ---------------- helpers ----------------
static __device__ __forceinline__ unsigned enc_min(float v) {
  unsigned u = __float_as_uint(v);
  return (u & 0x80000000u) ? ~u : (u | 0x80000000u);
}
static __device__ __forceinline__ unsigned short f2bf(float f) {
  unsigned u = __float_as_uint(f);
  u += 0x7fffu + ((u >> 16) & 1u);
  return (unsigned short)(u >> 16);
}
static __device__ __forceinline__ float bf2f(unsigned short b) {
  return __uint_as_float(((unsigned)b) << 16);
}
static __device__ __forceinline__ void acc8(float* a, uint4 v) {
  a[0] += __uint_as_float(v.x << 16);
  a[1] += __uint_as_float(v.x & 0xffff0000u);
  a[2] += __uint_as_float(v.y << 16);
  a[3] += __uint_as_float(v.y & 0xffff0000u);
  a[4] += __uint_as_float(v.z << 16);
  a[5] += __uint_as_float(v.z & 0xffff0000u);
  a[6] += __uint_as_float(v.w << 16);
  a[7] += __uint_as_float(v.w & 0xffff0000u);
}

// ---------------- pass A: bin edges into 256 dst-range buckets ----------------
// NO per-node global atomics (R9's 1.6M atomicAdd-with-return = 79us @ 1.6%
// VALU, ~50MB atomic write-through). LDS histogram gives the in-tile rank;
// ONE line-padded global reservation per bucket per 4096-edge tile (~100K
// total). Pure streaming otherwise.
__global__ __launch_bounds__(256) void k_binA(const int* __restrict__ edge, int E,
                                              int* __restrict__ bin_cur,  // stride 16 (line-padded)
                                              int2* __restrict__ pairs,
                                              int binw, int bcap) {
  __shared__ int h[NB], gbase[NB];
  int tid = threadIdx.x;
  int base = blockIdx.x * 4096;
  h[tid] = 0;
  if (tid + 0 == tid) {}  // no-op
  __syncthreads();
  int d_[16], s_[16], pk[16];
#pragma unroll
  for (int k = 0; k < 16; ++k) {
    int e = base + k * 256 + tid;
    d_[k] = -1;
    if (e < E) {
      int d = edge[E + e];
      int s = edge[e];
      int g = (int)((unsigned)d / (unsigned)binw);
      int rk = atomicAdd(&h[g], 1);           // LDS atomic: rank within tile-bucket
      pk[k] = (g << 16) | rk;                 // rk < 4096 fits 16b
      d_[k] = d;
      s_[k] = s;
    }
  }
  __syncthreads();
  if (h[tid] > 0) gbase[tid] = atomicAdd(&bin_cur[tid * 16], h[tid]);
  __syncthreads();
#pragma unroll
  for (int k = 0; k < 16; ++k) {
    if (d_[k] >= 0) {
      int g = pk[k] >> 16;
      int rk = pk[k] & 0xffff;
      int p = gbase[g] + rk;
      if (p < bcap) pairs[(size_t)g * bcap + p] = make_int2(d_[k], s_[k]);
    }
  }
}

// ---------------- exclusive scan of bucket totals (NB=256) ----------------
__global__ void k_scanB(const int* __restrict__ bin_cur, int* __restrict__ bucket_base) {
  __shared__ int sm[NB];
  int tid = threadIdx.x;
  int v = bin_cur[tid * 16];
  sm[tid] = v;
  __syncthreads();
  for (int off = 1; off < NB; off <<= 1) {
    int t = (tid >= off) ? sm[tid - off] : 0;
    __syncthreads();
    sm[tid] += t;
    __syncthreads();
  }
  bucket_base[tid] = sm[tid] - v;  // exclusive
}

// ---------------- pass B: per-bucket LDS count + scan + CSR build ----------------
// One block per bucket (<=391 dsts): count via LDS atomics, in-LDS scan ->
// row_ptr/dinv, then slot assignment via LDS cursor atomics; srcs writes land
// in the bucket's contiguous ~25KB CSR segment (L2-local).
__global__ __launch_bounds__(256) void k_buildB(const int2* __restrict__ pairs,
                                                const int* __restrict__ bin_cur,
                                                const int* __restrict__ bucket_base,
                                                int bcap, int binw, int N, int E,
                                                int* __restrict__ row_ptr,
                                                float* __restrict__ dinv,
                                                int* __restrict__ srcs) {
  __shared__ int cnt_s[512], cur_s[512], sm[512];
  int tid = threadIdx.x;
  int b = blockIdx.x;
  int d0 = b * binw;
  int dcnt = N - d0;
  if (dcnt > binw) dcnt = binw;
  if (dcnt < 0) dcnt = 0;
  int nb_e = bin_cur[b * 16];
  if (nb_e > bcap) nb_e = bcap;
  int bbase = bucket_base[b];
  const int2* pp = pairs + (size_t)b * bcap;

  cnt_s[tid] = 0;
  cnt_s[tid + 256] = 0;
  __syncthreads();
  for (int i = tid; i < nb_e; i += 256) {
    int2 pr = pp[i];
    atomicAdd(&cnt_s[pr.x - d0], 1);
  }
  __syncthreads();
  int c0 = cnt_s[tid], c1 = cnt_s[tid + 256];
  sm[tid] = c0;
  sm[tid + 256] = c1;
  __syncthreads();
  for (int off = 1; off < 512; off <<= 1) {
    int t0 = (tid >= off) ? sm[tid - off] : 0;
    int i1 = tid + 256;
    int t1 = (i1 >= off) ? sm[i1 - off] : 0;
    __syncthreads();
    sm[tid] += t0;
    sm[i1] += t1;
    __syncthreads();
  }
  int e0 = sm[tid] - c0, e1 = sm[tid + 256] - c1;
  if (tid < dcnt) {
    row_ptr[d0 + tid] = bbase + e0;
    dinv[d0 + tid] = 1.0f / sqrtf((float)(c0 + 1));
  }
  if (tid + 256 < dcnt) {
    row_ptr[d0 + tid + 256] = bbase + e1;
    dinv[d0 + tid + 256] = 1.0f / sqrtf((float)(c1 + 1));
  }
  cur_s[tid] = e0;
  cur_s[tid + 256] = e1;
  if (tid == 0 && d0 + dcnt == N) row_ptr[N] = E;
  __syncthreads();
  for (int i = tid; i < nb_e; i += 256) {
    int2 pr = pp[i];
    int slot = bbase + atomicAdd(&cur_s[pr.x - d0], 1);
    srcs[slot] = pr.y;
  }
}

// ---------------- weight prep: W[k][n] fp32 -> lane-ordered bf16 hi/lo fragments -----
__global__ void k_prepw(const float* __restrict__ W1, const float* __restrict__ W2,
                        const float* __restrict__ W3,
                        unsigned short* __restrict__ w1h, unsigned short* __restrict__ w1l,
                        unsigned short* __restrict__ w2h, unsigned short* __restrict__ w2l,
                        unsigned short* __restrict__ w3h, unsigned short* __restrict__ w3l) {
  const int K = 128;
  int idx = blockIdx.x * 256 + threadIdx.x;
  const float* W;
  unsigned short *oh, *ol;
  int Nn, base;
  if (idx < 16384) { W = W1; Nn = 128; oh = w1h; ol = w1l; base = idx; }
  else if (idx < 32768) { W = W2; Nn = 128; oh = w2h; ol = w2l; base = idx - 16384; }
  else if (idx < 40960) { W = W3; Nn = 64; oh = w3h; ol = w3l; base = idx - 32768; }
  else return;
  int n = base / K, k = base % K;
  float w = W[(size_t)k * Nn + n];
  unsigned short h = f2bf(w);
  unsigned short l = f2bf(w - bf2f(h));
  int nf = n >> 4, mloc = n & 15, kci = k >> 5, quad = (k >> 3) & 3, j = k & 7;
  size_t o = ((size_t)((nf * 4 + kci) * 64 + quad * 16 + mloc)) * 8 + j;
  oh[o] = h;
  ol[o] = l;
}

// ---------------- GEMM device body: fp32 A rows -> contiguous bf16 rows (dinv-scaled)
template <int NFW>
static __device__ __forceinline__ void gemm_body(const float* __restrict__ A,
                                                 const unsigned short* __restrict__ Wfh,
                                                 const unsigned short* __restrict__ Wfl,
                                                 const float* __restrict__ dinv,
                                                 unsigned short* __restrict__ P, int M,
                                                 int blk) {
  const int K = 128;
  const int COUT = NFW * 64;
  __shared__ unsigned short Ah[64][136];
  __shared__ unsigned short Al[64][136];
  int tid = threadIdx.x;
  int m0 = blk * 64;
  int w = tid >> 6, lane = tid & 63;

  bf16x8 bh[NFW][4], bl[NFW][4];
#pragma unroll
  for (int i = 0; i < NFW; ++i)
#pragma unroll
    for (int kci = 0; kci < 4; ++kci) {
      size_t o = ((size_t)(((w * NFW + i) * 4 + kci) * 64 + lane)) * 8;
      bh[i][kci] = *(const bf16x8*)&Wfh[o];
      bl[i][kci] = *(const bf16x8*)&Wfl[o];
    }

#pragma unroll
  for (int q = 0; q < 8; ++q) {
    int f = q * 256 + tid;
    int m = f >> 5, k4 = f & 31;
    int row = m0 + m;
    if (row >= M) row = M - 1;
    float4 v = *(const float4*)&A[(size_t)row * K + k4 * 4];
    unsigned short h0 = f2bf(v.x), h1 = f2bf(v.y), h2 = f2bf(v.z), h3 = f2bf(v.w);
    unsigned short l0 = f2bf(v.x - bf2f(h0)), l1 = f2bf(v.y - bf2f(h1));
    unsigned short l2 = f2bf(v.z - bf2f(h2)), l3 = f2bf(v.w - bf2f(h3));
    uint2 hh, ll;
    hh.x = (unsigned)h0 | ((unsigned)h1 << 16);
    hh.y = (unsigned)h2 | ((unsigned)h3 << 16);
    ll.x = (unsigned)l0 | ((unsigned)l1 << 16);
    ll.y = (unsigned)l2 | ((unsigned)l3 << 16);
    *(uint2*)&Ah[m][k4 * 4] = hh;
    *(uint2*)&Al[m][k4 * 4] = ll;
  }
  __syncthreads();

  int mloc = lane & 15, quad = lane >> 4;
  f32x4 acc[4][NFW];
#pragma unroll
  for (int rt = 0; rt < 4; ++rt)
#pragma unroll
    for (int i = 0; i < NFW; ++i) acc[rt][i] = (f32x4){0.f, 0.f, 0.f, 0.f};

#pragma unroll
  for (int rt = 0; rt < 4; ++rt) {
    const unsigned short* ph = &Ah[rt * 16 + mloc][quad * 8];
    const unsigned short* pl = &Al[rt * 16 + mloc][quad * 8];
#pragma unroll
    for (int kci = 0; kci < 4; ++kci) {
      bf16x8 ah = *(const bf16x8*)(ph + kci * 32);
      bf16x8 al = *(const bf16x8*)(pl + kci * 32);
#pragma unroll
      for (int i = 0; i < NFW; ++i) {
        acc[rt][i] = __builtin_amdgcn_mfma_f32_16x16x32_bf16(al, bh[i][kci], acc[rt][i], 0, 0, 0);
        acc[rt][i] = __builtin_amdgcn_mfma_f32_16x16x32_bf16(ah, bl[i][kci], acc[rt][i], 0, 0, 0);
        acc[rt][i] = __builtin_amdgcn_mfma_f32_16x16x32_bf16(ah, bh[i][kci], acc[rt][i], 0, 0, 0);
      }
    }
  }

#pragma unroll
  for (int rt = 0; rt < 4; ++rt) {
    int rbase = m0 + rt * 16 + quad * 4;
#pragma unroll
    for (int r = 0; r < 4; ++r) {
      int row = rbase + r;
      if (row < M) {
        float dv = dinv[row];
#pragma unroll
        for (int i = 0; i < NFW; ++i) {
          int nf = w * NFW + i;
          P[(size_t)row * COUT + nf * 16 + mloc] = f2bf(acc[rt][i][r] * dv);
        }
      }
    }
  }
}

// ---------------- standalone layer-1 GEMM (scatter now lives in k_buildB) ----------
__global__ __launch_bounds__(256) void k_gemm1(const float* __restrict__ A,
                                               const unsigned short* __restrict__ Wfh,
                                               const unsigned short* __restrict__ Wfl,
                                               const float* __restrict__ dinv,
                                               unsigned short* __restrict__ P, int M) {
  gemm_body<2>(A, Wfh, Wfl, dinv, P, M, blockIdx.x);
}

// ---------------- FUSED per-layer: gather (8-deep MLP) -> H tile -> MFMA -> Pout -----
template <int NFW>  // output channels = NFW*64
__global__ __launch_bounds__(256) void k_agg_gemm(const unsigned short* __restrict__ Pin,
                                                  const int* __restrict__ row_ptr,
                                                  const int* __restrict__ srcs,
                                                  const float* __restrict__ dinv,
                                                  const float* __restrict__ bias,
                                                  const unsigned short* __restrict__ Wfh,
                                                  const unsigned short* __restrict__ Wfl,
                                                  unsigned short* __restrict__ Pout, int N) {
  const int COUT = NFW * 64;
  __shared__ unsigned short Ah[16][136];
  __shared__ unsigned short Al[16][136];
  int tid = threadIdx.x;
  int wv = tid >> 6, lane = tid & 63;
  int grp = lane >> 4, sub = lane & 15;
  int m = wv * 4 + grp;                 // row in 16-row tile
  int d = blockIdx.x * 16 + m;
  int dc = d < N ? d : N - 1;
  bool valid = d < N;
  unsigned soff = (unsigned)sub * 16u;  // byte offset in 256B row
  const char* Pb = (const char*)Pin;

  float a[8] = {0.f, 0.f, 0.f, 0.f, 0.f, 0.f, 0.f, 0.f};
  {  // self-loop contribution = own row
    uint4 v = *(const uint4*)(Pb + ((unsigned)dc * 256u + soff));
    acc8(a, v);
  }
  int lo = row_ptr[dc];
  int hi = row_ptr[valid ? d + 1 : dc];
  int j = lo;
  for (; j + 8 <= hi; j += 8) {
    unsigned id[8];
    uint4 vv[8];
#pragma unroll
    for (int k = 0; k < 8; ++k) id[k] = (unsigned)srcs[j + k];
#pragma unroll
    for (int k = 0; k < 8; ++k) vv[k] = *(const uint4*)(Pb + (id[k] * 256u + soff));
#pragma unroll
    for (int k = 0; k < 8; ++k) acc8(a, vv[k]);
  }
  for (; j + 4 <= hi; j += 4) {
    unsigned id[4];
    uint4 vv[4];
#pragma unroll
    for (int k = 0; k < 4; ++k) id[k] = (unsigned)srcs[j + k];
#pragma unroll
    for (int k = 0; k < 4; ++k) vv[k] = *(const uint4*)(Pb + (id[k] * 256u + soff));
#pragma unroll
    for (int k = 0; k < 4; ++k) acc8(a, vv[k]);
  }
  for (; j < hi; ++j) {
    unsigned i0 = (unsigned)srcs[j];
    uint4 v0 = *(const uint4*)(Pb + (i0 * 256u + soff));
    acc8(a, v0);
  }

  // weight fragments (issued here: overlap with epilogue VALU + barrier)
  bf16x8 bh[NFW][4], bl[NFW][4];
#pragma unroll
  for (int i = 0; i < NFW; ++i)
#pragma unroll
    for (int kci = 0; kci < 4; ++kci) {
      size_t o = ((size_t)(((wv * NFW + i) * 4 + kci) * 64 + lane)) * 8;
      bh[i][kci] = *(const bf16x8*)&Wfh[o];
      bl[i][kci] = *(const bf16x8*)&Wfl[o];
    }

  // H = relu(dinv*agg + bias) -> bf16 hi/lo -> LDS
  float dv = dinv[dc];
  int ch0 = sub * 8;
  float4 bv0 = *(const float4*)&bias[ch0];
  float4 bv1 = *(const float4*)&bias[ch0 + 4];
  float h[8];
  h[0] = dv * a[0] + bv0.x; h[1] = dv * a[1] + bv0.y;
  h[2] = dv * a[2] + bv0.z; h[3] = dv * a[3] + bv0.w;
  h[4] = dv * a[4] + bv1.x; h[5] = dv * a[5] + bv1.y;
  h[6] = dv * a[6] + bv1.z; h[7] = dv * a[7] + bv1.w;
#pragma unroll
  for (int k = 0; k < 8; ++k) h[k] = fmaxf(h[k], 0.f);
  unsigned short hb[8], lb[8];
#pragma unroll
  for (int k = 0; k < 8; ++k) {
    hb[k] = f2bf(h[k]);
    lb[k] = f2bf(h[k] - bf2f(hb[k]));
  }
  uint4 HH, LL;
  HH.x = (unsigned)hb[0] | ((unsigned)hb[1] << 16);
  HH.y = (unsigned)hb[2] | ((unsigned)hb[3] << 16);
  HH.z = (unsigned)hb[4] | ((unsigned)hb[5] << 16);
  HH.w = (unsigned)hb[6] | ((unsigned)hb[7] << 16);
  LL.x = (unsigned)lb[0] | ((unsigned)lb[1] << 16);
  LL.y = (unsigned)lb[2] | ((unsigned)lb[3] << 16);
  LL.z = (unsigned)lb[4] | ((unsigned)lb[5] << 16);
  LL.w = (unsigned)lb[6] | ((unsigned)lb[7] << 16);
  *(uint4*)&Ah[m][ch0] = HH;
  *(uint4*)&Al[m][ch0] = LL;
  __syncthreads();

  // MFMA: 16 rows x COUT, K=128 -> Pout rows scaled by dinv[row]
  int mloc = lane & 15, quad = lane >> 4;
  f32x4 acc[NFW];
#pragma unroll
  for (int i = 0; i < NFW; ++i) acc[i] = (f32x4){0.f, 0.f, 0.f, 0.f};
#pragma unroll
  for (int kci = 0; kci < 4; ++kci) {
    bf16x8 ah = *(const bf16x8*)&Ah[mloc][quad * 8 + kci * 32];
    bf16x8 al = *(const bf16x8*)&Al[mloc][quad * 8 + kci * 32];
#pragma unroll
    for (int i = 0; i < NFW; ++i) {
      acc[i] = __builtin_amdgcn_mfma_f32_16x16x32_bf16(al, bh[i][kci], acc[i], 0, 0, 0);
      acc[i] = __builtin_amdgcn_mfma_f32_16x16x32_bf16(ah, bl[i][kci], acc[i], 0, 0, 0);
      acc[i] = __builtin_amdgcn_mfma_f32_16x16x32_bf16(ah, bh[i][kci], acc[i], 0, 0, 0);
    }
  }
  int rbase = blockIdx.x * 16 + quad * 4;
#pragma unroll
  for (int r = 0; r < 4; ++r) {
    int row = rbase + r;
    if (row < N) {
      float dvr = dinv[row];
#pragma unroll
      for (int i = 0; i < NFW; ++i) {
        int nf = wv * NFW + i;
        Pout[(size_t)row * COUT + nf * 16 + mloc] = f2bf(acc[i][r] * dvr);
      }
    }
  }
}

// ---------------- final layer: R3-verified sliced staged aggregation + min-pool -----
__global__ __launch_bounds__(256) void k_agg_pool(const unsigned short* __restrict__ P,
                                                  const int* __restrict__ row_ptr,
                                                  const int* __restrict__ srcs,
                                                  const float* __restrict__ dinv,
                                                  const float* __restrict__ bias,
                                                  unsigned* __restrict__ minenc, int N) {
  const int CAP = 448;
  __shared__ int s_idx[4][CAP];
  __shared__ float s_red[4][32];
  int tid = threadIdx.x;
  int wv = tid >> 6, lane = tid & 63;
  int b8 = blockIdx.x & 7;
  int slice = b8 >> 2, part = b8 & 3;  // 2 slices x 4 parts
  int g0 = ((blockIdx.x >> 3) * 4 + part) * 64 + wv * 16;
  const char* Pb = (const char*)P + slice * 64;  // rows are 128B contiguous

  int i = lane >> 2, q = lane & 3;
  unsigned qoff = (unsigned)q * 16u;
  int d = g0 + i;
  int dc = d < N ? d : N - 1;
  bool valid = d < N;

  int e0 = row_ptr[g0 < N ? g0 : N];
  int e1 = row_ptr[(g0 + 16) < N ? (g0 + 16) : N];
  int lo_n = row_ptr[dc];
  int hi_n = row_ptr[valid ? d + 1 : dc];

  float a[8];
  {
    uint4 v = *(const uint4*)(Pb + ((unsigned)dc * 128u + qoff));
    a[0] = __uint_as_float(v.x << 16);
    a[1] = __uint_as_float(v.x & 0xffff0000u);
    a[2] = __uint_as_float(v.y << 16);
    a[3] = __uint_as_float(v.y & 0xffff0000u);
    a[4] = __uint_as_float(v.z << 16);
    a[5] = __uint_as_float(v.z & 0xffff0000u);
    a[6] = __uint_as_float(v.w << 16);
    a[7] = __uint_as_float(v.w & 0xffff0000u);
  }

  for (int w0 = e0; w0 < e1; w0 += CAP) {
    int wend = min(w0 + CAP, e1);
    int cnt = wend - w0;
    __builtin_amdgcn_wave_barrier();
    for (int t = lane; t < cnt; t += 64) s_idx[wv][t] = srcs[w0 + t];
    __builtin_amdgcn_wave_barrier();
    int j = max(lo_n, w0), hi = min(hi_n, wend);
    for (; j + 4 <= hi; j += 4) {
      unsigned i0 = (unsigned)s_idx[wv][j - w0];
      unsigned i1 = (unsigned)s_idx[wv][j - w0 + 1];
      unsigned i2 = (unsigned)s_idx[wv][j - w0 + 2];
      unsigned i3 = (unsigned)s_idx[wv][j - w0 + 3];
      uint4 v0 = *(const uint4*)(Pb + (i0 * 128u + qoff));
      uint4 v1 = *(const uint4*)(Pb + (i1 * 128u + qoff));
      uint4 v2 = *(const uint4*)(Pb + (i2 * 128u + qoff));
      uint4 v3 = *(const uint4*)(Pb + (i3 * 128u + qoff));
      acc8(a, v0);
      acc8(a, v1);
      acc8(a, v2);
      acc8(a, v3);
    }
    for (; j < hi; ++j) {
      unsigned i0 = (unsigned)s_idx[wv][j - w0];
      uint4 v0 = *(const uint4*)(Pb + (i0 * 128u + qoff));
      acc8(a, v0);
    }
  }

  int c0 = slice * 32 + q * 8;
  float dv = dinv[dc];
  float4 bv0 = *(const float4*)&bias[c0];
  float4 bv1 = *(const float4*)&bias[c0 + 4];
  float h[8];
  h[0] = dv * a[0] + bv0.x; h[1] = dv * a[1] + bv0.y;
  h[2] = dv * a[2] + bv0.z; h[3] = dv * a[3] + bv0.w;
  h[4] = dv * a[4] + bv1.x; h[5] = dv * a[5] + bv1.y;
  h[6] = dv * a[6] + bv1.z; h[7] = dv * a[7] + bv1.w;

  if (!valid) {
#pragma unroll
    for (int k = 0; k < 8; ++k) h[k] = FLT_MAX;
  }
#pragma unroll
  for (int off = 4; off < 64; off <<= 1) {
#pragma unroll
    for (int k = 0; k < 8; ++k) h[k] = fminf(h[k], __shfl_xor(h[k], off, 64));
  }
  if (lane < 4) {
#pragma unroll
    for (int k = 0; k < 8; ++k) s_red[wv][q * 8 + k] = h[k];
  }
  __syncthreads();
  if (tid < 32) {
    float mn = fminf(fminf(s_red[0][tid], s_red[1][tid]),
                     fminf(s_red[2][tid], s_red[3][tid]));
    atomicMin(&minenc[slice * 32 + tid], enc_min(mn));
  }
}

__global__ void k_decode(const unsigned* __restrict__ minenc, float* __restrict__ out) {
  int c = threadIdx.x;
  unsigned k = minenc[c];
  unsigned u = (k & 0x80000000u) ? (k & 0x7FFFFFFFu) : ~k;
  out[c] = __uint_as_float(u);
}

// ---------------- launch ----------------
extern "C" void kernel_launch(void* const* d_in, const int* in_sizes, int n_in,
                              void* d_out, int out_size, void* d_ws, size_t ws_size,
                              hipStream_t stream) {
  const float* X  = (const float*)d_in[0];
  const int* edge = (const int*)d_in[1];
  const float* W1 = (const float*)d_in[2];
  const float* b1 = (const float*)d_in[3];
  const float* W2 = (const float*)d_in[4];
  const float* b2 = (const float*)d_in[5];
  const float* W3 = (const float*)d_in[6];
  const float* b3 = (const float*)d_in[7];
  float* out = (float*)d_out;

  const int IN_CH = 128;
  int N = in_sizes[0] / IN_CH;
  int E = in_sizes[1] / 2;

  char* ws = (char*)d_ws;
  size_t off = 0;
  auto alloc = [&](size_t bytes) {
    void* p = ws + off;
    off = (off + bytes + 255) & ~(size_t)255;
    return p;
  };
  unsigned short* P1 = (unsigned short*)alloc((size_t)N * 128 * 2);  // 25.6 MB, 256B rows
  unsigned short* P2 = (unsigned short*)alloc((size_t)N * 128 * 2);  // 25.6 MB
  int* srcs      = (int*)alloc((size_t)E * 4);                       // 6.4 MB
  int* row_ptr   = (int*)alloc((size_t)(N + 1) * 4);
  float* dinv    = (float*)alloc((size_t)N * 4);
  int* bin_cur   = (int*)alloc((size_t)NB * 16 * 4);  // line-padded (stride 16 ints)
  int* bucket_base = (int*)alloc((size_t)NB * 4);
  unsigned* minenc = (unsigned*)alloc(256);
  unsigned short* w1h = (unsigned short*)alloc(16384 * 2);
  unsigned short* w1l = (unsigned short*)alloc(16384 * 2);
  unsigned short* w2h = (unsigned short*)alloc(16384 * 2);
  unsigned short* w2l = (unsigned short*)alloc(16384 * 2);
  unsigned short* w3h = (unsigned short*)alloc(8192 * 2);
  unsigned short* w3l = (unsigned short*)alloc(8192 * 2);

  // Aliases (lifetime-checked):
  //  pairs -> P2 region: written by k_binA, consumed (twice) by k_buildB,
  //           both strictly before k_agg_gemm<2> writes P2.
  //  P3    -> P1 region: P1 last read by k_agg_gemm<2>; k_agg_gemm<1> reads P2
  //           and writes P3.
  int binw = (N + NB - 1) / NB;              // 391 @ N=100K (<=512 LDS counters)
  int bcap = E / NB + 1024;                  // Poisson(6250), +1024 = 32 sigma
  int2* pairs = (int2*)P2;                   // NB*bcap*8B = 14.9 MB <= 25.6 MB
  unsigned short* P3 = P1;

  hipMemsetAsync(bin_cur, 0, (size_t)NB * 16 * 4, stream);
  hipMemsetAsync(minenc, 0xFF, 64 * 4, stream);  // encoded +max

  int gx = (N + 63) / 64;
  int nta = (E + 4095) / 4096;
  int gagg = (N + 15) / 16;
  int c64 = (N + 255) / 256;
  k_prepw<<<160, 256, 0, stream>>>(W1, W2, W3, w1h, w1l, w2h, w2l, w3h, w3l);
  // front-end: bin -> scan -> build (replaces count+scan1+scan2+aux+scatter)
  k_binA<<<nta, 256, 0, stream>>>(edge, E, bin_cur, pairs, binw, bcap);
  k_scanB<<<1, NB, 0, stream>>>(bin_cur, bucket_base);
  k_buildB<<<NB, 256, 0, stream>>>(pairs, bin_cur, bucket_base, bcap, binw, N, E,
                                   row_ptr, dinv, srcs);
  // layer 1 transform: X*W1 -> P1 (rows scaled by dinv)
  k_gemm1<<<gx, 256, 0, stream>>>(X, w1h, w1l, dinv, P1, N);
  // layer 1 agg + layer 2 gemm fused: P1 -> (H1) -> P2
  k_agg_gemm<2><<<gagg, 256, 0, stream>>>(P1, row_ptr, srcs, dinv, b1, w2h, w2l, P2, N);
  // layer 2 agg + layer 3 gemm fused: P2 -> (H2) -> P3
  k_agg_gemm<1><<<gagg, 256, 0, stream>>>(P2, row_ptr, srcs, dinv, b2, w3h, w3l, P3, N);
  // layer 3 agg + bias + min-pool (R3 staged variant)
  k_agg_pool<<<c64 * 8, 256, 0, stream>>>(P3, row_ptr, srcs, dinv, b3, minenc, N);
  // decode encoded mins -> out[64]
  k_decode<<<1, 64, 0, stream>>>(minenc, out);
}

// Round 11
// 355.505 us; speedup vs baseline: 1.3248x; 1.0201x over previous
//
#include <hip/hip_runtime.h>
#include <stdint.h>
#include <stddef.h>
#include <float.h>

typedef short bf16x8 __attribute__((ext_vector_type(8)));
typedef float f32x4 __attribute__((ext_vector_type(4)));

#define NB 256  // dst-range buckets; binw = ceil(N/256) = 391 @ N=100K -> LDS counters fit

// ---------------- helpers ----------------
static __device__ __forceinline__ unsigned enc_min(float v) {
  unsigned u = __float_as_uint(v);
  return (u & 0x80000000u) ? ~u : (u | 0x80000000u);
}
static __device__ __forceinline__ unsigned short f2bf(float f) {
  unsigned u = __float_as_uint(f);
  u += 0x7fffu + ((u >> 16) & 1u);
  return (unsigned short)(u >> 16);
}
static __device__ __forceinline__ float bf2f(unsigned short b) {
  return __uint_as_float(((unsigned)b) << 16);
}
static __device__ __forceinline__ void acc8(float* a, uint4 v) {
  a[0] += __uint_as_float(v.x << 16);
  a[1] += __uint_as_float(v.x & 0xffff0000u);
  a[2] += __uint_as_float(v.y << 16);
  a[3] += __uint_as_float(v.y & 0xffff0000u);
  a[4] += __uint_as_float(v.z << 16);
  a[5] += __uint_as_float(v.z & 0xffff0000u);
  a[6] += __uint_as_float(v.w << 16);
  a[7] += __uint_as_float(v.w & 0xffff0000u);
}

// ---------------- FUSED pass A: edge binning (blocks < nta) + weight prep (rest) ----
// Binning: NO per-node global atomics (R10-verified). LDS histogram gives the
// in-tile rank; ONE line-padded global reservation per bucket per 4096-edge
// tile. Weight prep (tiny streaming job) rides on the trailing blocks.
__global__ __launch_bounds__(256) void k_bin_prep(const int* __restrict__ edge, int E,
                                                  int* __restrict__ bin_cur,  // stride 16
                                                  int2* __restrict__ pairs,
                                                  int binw, int bcap, int nta,
                                                  const float* __restrict__ W1,
                                                  const float* __restrict__ W2,
                                                  const float* __restrict__ W3,
                                                  unsigned short* __restrict__ w1h,
                                                  unsigned short* __restrict__ w1l,
                                                  unsigned short* __restrict__ w2h,
                                                  unsigned short* __restrict__ w2l,
                                                  unsigned short* __restrict__ w3h,
                                                  unsigned short* __restrict__ w3l) {
  int tid = threadIdx.x;
  if ((int)blockIdx.x >= nta) {
    // ---- weight prep: W[k][n] fp32 -> lane-ordered bf16 hi/lo fragments ----
    const int K = 128;
    int idx = ((int)blockIdx.x - nta) * 256 + tid;
    const float* W;
    unsigned short *oh, *ol;
    int Nn, base;
    if (idx < 16384) { W = W1; Nn = 128; oh = w1h; ol = w1l; base = idx; }
    else if (idx < 32768) { W = W2; Nn = 128; oh = w2h; ol = w2l; base = idx - 16384; }
    else if (idx < 40960) { W = W3; Nn = 64; oh = w3h; ol = w3l; base = idx - 32768; }
    else return;
    int n = base / K, k = base % K;
    float w = W[(size_t)k * Nn + n];
    unsigned short h = f2bf(w);
    unsigned short l = f2bf(w - bf2f(h));
    int nf = n >> 4, mloc = n & 15, kci = k >> 5, quad = (k >> 3) & 3, j = k & 7;
    size_t o = ((size_t)((nf * 4 + kci) * 64 + quad * 16 + mloc)) * 8 + j;
    oh[o] = h;
    ol[o] = l;
    return;
  }
  __shared__ int h[NB], gbase[NB];
  int base = blockIdx.x * 4096;
  h[tid] = 0;
  __syncthreads();
  int d_[16], s_[16], pk[16];
#pragma unroll
  for (int k = 0; k < 16; ++k) {
    int e = base + k * 256 + tid;
    d_[k] = -1;
    if (e < E) {
      int d = edge[E + e];
      int s = edge[e];
      int g = (int)((unsigned)d / (unsigned)binw);
      int rk = atomicAdd(&h[g], 1);           // LDS atomic: rank within tile-bucket
      pk[k] = (g << 16) | rk;                 // rk < 4096 fits 16b
      d_[k] = d;
      s_[k] = s;
    }
  }
  __syncthreads();
  if (h[tid] > 0) gbase[tid] = atomicAdd(&bin_cur[tid * 16], h[tid]);
  __syncthreads();
#pragma unroll
  for (int k = 0; k < 16; ++k) {
    if (d_[k] >= 0) {
      int g = pk[k] >> 16;
      int rk = pk[k] & 0xffff;
      int p = gbase[g] + rk;
      if (p < bcap) pairs[(size_t)g * bcap + p] = make_int2(d_[k], s_[k]);
    }
  }
}

// ---------------- pass B1: per-bucket LDS count + scan -> row_ptr / dinv ------------
// One block per bucket (<=391 dsts). Each block computes its own bucket base
// by scanning the 256 line-padded totals in LDS (replaces the k_scanB launch).
// The CSR slot-assignment (scatter) moved to k_scatter_gemm, where it hides
// under GEMM1 (dinv produced here unblocks the GEMM epilogue).
__global__ __launch_bounds__(256) void k_buildB1(const int* __restrict__ bin_cur,
                                                 const int2* __restrict__ pairs,
                                                 int bcap, int binw, int N, int E,
                                                 int* __restrict__ row_ptr,
                                                 float* __restrict__ dinv) {
  __shared__ int tot[NB];
  __shared__ int cnt_s[512], sm[512];
  int tid = threadIdx.x;
  int b = blockIdx.x;
  // own bucket base = exclusive prefix of bucket totals
  tot[tid] = bin_cur[tid * 16];
  __syncthreads();
  for (int off = 1; off < NB; off <<= 1) {
    int t = (tid >= off) ? tot[tid - off] : 0;
    __syncthreads();
    tot[tid] += t;
    __syncthreads();
  }
  int bbase = (b == 0) ? 0 : tot[b - 1];
  int nb_e = bin_cur[b * 16];
  if (nb_e > bcap) nb_e = bcap;

  int d0 = b * binw;
  int dcnt = N - d0;
  if (dcnt > binw) dcnt = binw;
  if (dcnt < 0) dcnt = 0;
  const int2* pp = pairs + (size_t)b * bcap;

  cnt_s[tid] = 0;
  cnt_s[tid + 256] = 0;
  __syncthreads();
  for (int i = tid; i < nb_e; i += 256) {
    int2 pr = pp[i];
    atomicAdd(&cnt_s[pr.x - d0], 1);
  }
  __syncthreads();
  int c0 = cnt_s[tid], c1 = cnt_s[tid + 256];
  sm[tid] = c0;
  sm[tid + 256] = c1;
  __syncthreads();
  for (int off = 1; off < 512; off <<= 1) {
    int t0 = (tid >= off) ? sm[tid - off] : 0;
    int i1 = tid + 256;
    int t1 = (i1 >= off) ? sm[i1 - off] : 0;
    __syncthreads();
    sm[tid] += t0;
    sm[i1] += t1;
    __syncthreads();
  }
  int e0 = sm[tid] - c0, e1 = sm[tid + 256] - c1;
  if (tid < dcnt) {
    row_ptr[d0 + tid] = bbase + e0;
    dinv[d0 + tid] = 1.0f / sqrtf((float)(c0 + 1));
  }
  if (tid + 256 < dcnt) {
    row_ptr[d0 + tid + 256] = bbase + e1;
    dinv[d0 + tid + 256] = 1.0f / sqrtf((float)(c1 + 1));
  }
  if (tid == 0 && d0 + dcnt == N) row_ptr[N] = E;
}

// ---------------- GEMM device body: fp32 A rows -> contiguous bf16 rows (dinv-scaled)
template <int NFW>
static __device__ __forceinline__ void gemm_body(const float* __restrict__ A,
                                                 const unsigned short* __restrict__ Wfh,
                                                 const unsigned short* __restrict__ Wfl,
                                                 const float* __restrict__ dinv,
                                                 unsigned short* __restrict__ P, int M,
                                                 int blk) {
  const int K = 128;
  const int COUT = NFW * 64;
  __shared__ unsigned short Ah[64][136];
  __shared__ unsigned short Al[64][136];
  int tid = threadIdx.x;
  int m0 = blk * 64;
  int w = tid >> 6, lane = tid & 63;

  bf16x8 bh[NFW][4], bl[NFW][4];
#pragma unroll
  for (int i = 0; i < NFW; ++i)
#pragma unroll
    for (int kci = 0; kci < 4; ++kci) {
      size_t o = ((size_t)(((w * NFW + i) * 4 + kci) * 64 + lane)) * 8;
      bh[i][kci] = *(const bf16x8*)&Wfh[o];
      bl[i][kci] = *(const bf16x8*)&Wfl[o];
    }

#pragma unroll
  for (int q = 0; q < 8; ++q) {
    int f = q * 256 + tid;
    int m = f >> 5, k4 = f & 31;
    int row = m0 + m;
    if (row >= M) row = M - 1;
    float4 v = *(const float4*)&A[(size_t)row * K + k4 * 4];
    unsigned short h0 = f2bf(v.x), h1 = f2bf(v.y), h2 = f2bf(v.z), h3 = f2bf(v.w);
    unsigned short l0 = f2bf(v.x - bf2f(h0)), l1 = f2bf(v.y - bf2f(h1));
    unsigned short l2 = f2bf(v.z - bf2f(h2)), l3 = f2bf(v.w - bf2f(h3));
    uint2 hh, ll;
    hh.x = (unsigned)h0 | ((unsigned)h1 << 16);
    hh.y = (unsigned)h2 | ((unsigned)h3 << 16);
    ll.x = (unsigned)l0 | ((unsigned)l1 << 16);
    ll.y = (unsigned)l2 | ((unsigned)l3 << 16);
    *(uint2*)&Ah[m][k4 * 4] = hh;
    *(uint2*)&Al[m][k4 * 4] = ll;
  }
  __syncthreads();

  int mloc = lane & 15, quad = lane >> 4;
  f32x4 acc[4][NFW];
#pragma unroll
  for (int rt = 0; rt < 4; ++rt)
#pragma unroll
    for (int i = 0; i < NFW; ++i) acc[rt][i] = (f32x4){0.f, 0.f, 0.f, 0.f};

#pragma unroll
  for (int rt = 0; rt < 4; ++rt) {
    const unsigned short* ph = &Ah[rt * 16 + mloc][quad * 8];
    const unsigned short* pl = &Al[rt * 16 + mloc][quad * 8];
#pragma unroll
    for (int kci = 0; kci < 4; ++kci) {
      bf16x8 ah = *(const bf16x8*)(ph + kci * 32);
      bf16x8 al = *(const bf16x8*)(pl + kci * 32);
#pragma unroll
      for (int i = 0; i < NFW; ++i) {
        acc[rt][i] = __builtin_amdgcn_mfma_f32_16x16x32_bf16(al, bh[i][kci], acc[rt][i], 0, 0, 0);
        acc[rt][i] = __builtin_amdgcn_mfma_f32_16x16x32_bf16(ah, bl[i][kci], acc[rt][i], 0, 0, 0);
        acc[rt][i] = __builtin_amdgcn_mfma_f32_16x16x32_bf16(ah, bh[i][kci], acc[rt][i], 0, 0, 0);
      }
    }
  }

#pragma unroll
  for (int rt = 0; rt < 4; ++rt) {
    int rbase = m0 + rt * 16 + quad * 4;
#pragma unroll
    for (int r = 0; r < 4; ++r) {
      int row = rbase + r;
      if (row < M) {
        float dv = dinv[row];
#pragma unroll
        for (int i = 0; i < NFW; ++i) {
          int nf = w * NFW + i;
          P[(size_t)row * COUT + nf * 16 + mloc] = f2bf(acc[rt][i][r] * dv);
        }
      }
    }
  }
}

// ---------------- FUSED: LDS-cursor CSR scatter (blocks < NB) + layer-1 GEMM --------
// Scatter blocks (one per bucket) init LDS cursors straight from row_ptr --
// no recount, no global atomics -- and drain inside the GEMM family's shadow
// (R3/R9-verified pattern). srcs writes land in the bucket's contiguous ~25KB
// CSR segment (L2-local).
__global__ __launch_bounds__(256) void k_scatter_gemm(const float* __restrict__ A,
                                                      const unsigned short* __restrict__ Wfh,
                                                      const unsigned short* __restrict__ Wfl,
                                                      const float* __restrict__ dinv,
                                                      unsigned short* __restrict__ P, int M,
                                                      const int2* __restrict__ pairs,
                                                      const int* __restrict__ bin_cur, int bcap,
                                                      const int* __restrict__ row_ptr,
                                                      int binw, int N,
                                                      int* __restrict__ srcs) {
  if ((int)blockIdx.x >= NB) {
    gemm_body<2>(A, Wfh, Wfl, dinv, P, M, blockIdx.x - NB);
    return;
  }
  __shared__ int cur_s[512];
  int tid = threadIdx.x;
  int b = blockIdx.x;
  int d0 = b * binw;
  int dcnt = N - d0;
  if (dcnt > binw) dcnt = binw;
  if (dcnt < 0) dcnt = 0;
  int nb_e = bin_cur[b * 16];
  if (nb_e > bcap) nb_e = bcap;
  const int2* pp = pairs + (size_t)b * bcap;
  if (tid < dcnt) cur_s[tid] = row_ptr[d0 + tid];
  if (tid + 256 < dcnt) cur_s[tid + 256] = row_ptr[d0 + tid + 256];
  __syncthreads();
  for (int i = tid; i < nb_e; i += 256) {
    int2 pr = pp[i];
    srcs[atomicAdd(&cur_s[pr.x - d0], 1)] = pr.y;
  }
}

// ---------------- FUSED per-layer: gather (8-deep MLP) -> H tile -> MFMA -> Pout -----
template <int NFW>  // output channels = NFW*64
__global__ __launch_bounds__(256) void k_agg_gemm(const unsigned short* __restrict__ Pin,
                                                  const int* __restrict__ row_ptr,
                                                  const int* __restrict__ srcs,
                                                  const float* __restrict__ dinv,
                                                  const float* __restrict__ bias,
                                                  const unsigned short* __restrict__ Wfh,
                                                  const unsigned short* __restrict__ Wfl,
                                                  unsigned short* __restrict__ Pout, int N) {
  const int COUT = NFW * 64;
  __shared__ unsigned short Ah[16][136];
  __shared__ unsigned short Al[16][136];
  int tid = threadIdx.x;
  int wv = tid >> 6, lane = tid & 63;
  int grp = lane >> 4, sub = lane & 15;
  int m = wv * 4 + grp;                 // row in 16-row tile
  int d = blockIdx.x * 16 + m;
  int dc = d < N ? d : N - 1;
  bool valid = d < N;
  unsigned soff = (unsigned)sub * 16u;  // byte offset in 256B row
  const char* Pb = (const char*)Pin;

  float a[8] = {0.f, 0.f, 0.f, 0.f, 0.f, 0.f, 0.f, 0.f};
  {  // self-loop contribution = own row
    uint4 v = *(const uint4*)(Pb + ((unsigned)dc * 256u + soff));
    acc8(a, v);
  }
  int lo = row_ptr[dc];
  int hi = row_ptr[valid ? d + 1 : dc];
  int j = lo;
  for (; j + 8 <= hi; j += 8) {
    unsigned id[8];
    uint4 vv[8];
#pragma unroll
    for (int k = 0; k < 8; ++k) id[k] = (unsigned)srcs[j + k];
#pragma unroll
    for (int k = 0; k < 8; ++k) vv[k] = *(const uint4*)(Pb + (id[k] * 256u + soff));
#pragma unroll
    for (int k = 0; k < 8; ++k) acc8(a, vv[k]);
  }
  for (; j + 4 <= hi; j += 4) {
    unsigned id[4];
    uint4 vv[4];
#pragma unroll
    for (int k = 0; k < 4; ++k) id[k] = (unsigned)srcs[j + k];
#pragma unroll
    for (int k = 0; k < 4; ++k) vv[k] = *(const uint4*)(Pb + (id[k] * 256u + soff));
#pragma unroll
    for (int k = 0; k < 4; ++k) acc8(a, vv[k]);
  }
  for (; j < hi; ++j) {
    unsigned i0 = (unsigned)srcs[j];
    uint4 v0 = *(const uint4*)(Pb + (i0 * 256u + soff));
    acc8(a, v0);
  }

  // weight fragments (issued here: overlap with epilogue VALU + barrier)
  bf16x8 bh[NFW][4], bl[NFW][4];
#pragma unroll
  for (int i = 0; i < NFW; ++i)
#pragma unroll
    for (int kci = 0; kci < 4; ++kci) {
      size_t o = ((size_t)(((wv * NFW + i) * 4 + kci) * 64 + lane)) * 8;
      bh[i][kci] = *(const bf16x8*)&Wfh[o];
      bl[i][kci] = *(const bf16x8*)&Wfl[o];
    }

  // H = relu(dinv*agg + bias) -> bf16 hi/lo -> LDS
  float dv = dinv[dc];
  int ch0 = sub * 8;
  float4 bv0 = *(const float4*)&bias[ch0];
  float4 bv1 = *(const float4*)&bias[ch0 + 4];
  float h[8];
  h[0] = dv * a[0] + bv0.x; h[1] = dv * a[1] + bv0.y;
  h[2] = dv * a[2] + bv0.z; h[3] = dv * a[3] + bv0.w;
  h[4] = dv * a[4] + bv1.x; h[5] = dv * a[5] + bv1.y;
  h[6] = dv * a[6] + bv1.z; h[7] = dv * a[7] + bv1.w;
#pragma unroll
  for (int k = 0; k < 8; ++k) h[k] = fmaxf(h[k], 0.f);
  unsigned short hb[8], lb[8];
#pragma unroll
  for (int k = 0; k < 8; ++k) {
    hb[k] = f2bf(h[k]);
    lb[k] = f2bf(h[k] - bf2f(hb[k]));
  }
  uint4 HH, LL;
  HH.x = (unsigned)hb[0] | ((unsigned)hb[1] << 16);
  HH.y = (unsigned)hb[2] | ((unsigned)hb[3] << 16);
  HH.z = (unsigned)hb[4] | ((unsigned)hb[5] << 16);
  HH.w = (unsigned)hb[6] | ((unsigned)hb[7] << 16);
  LL.x = (unsigned)lb[0] | ((unsigned)lb[1] << 16);
  LL.y = (unsigned)lb[2] | ((unsigned)lb[3] << 16);
  LL.z = (unsigned)lb[4] | ((unsigned)lb[5] << 16);
  LL.w = (unsigned)lb[6] | ((unsigned)lb[7] << 16);
  *(uint4*)&Ah[m][ch0] = HH;
  *(uint4*)&Al[m][ch0] = LL;
  __syncthreads();

  // MFMA: 16 rows x COUT, K=128 -> Pout rows scaled by dinv[row]
  int mloc = lane & 15, quad = lane >> 4;
  f32x4 acc[NFW];
#pragma unroll
  for (int i = 0; i < NFW; ++i) acc[i] = (f32x4){0.f, 0.f, 0.f, 0.f};
#pragma unroll
  for (int kci = 0; kci < 4; ++kci) {
    bf16x8 ah = *(const bf16x8*)&Ah[mloc][quad * 8 + kci * 32];
    bf16x8 al = *(const bf16x8*)&Al[mloc][quad * 8 + kci * 32];
#pragma unroll
    for (int i = 0; i < NFW; ++i) {
      acc[i] = __builtin_amdgcn_mfma_f32_16x16x32_bf16(al, bh[i][kci], acc[i], 0, 0, 0);
      acc[i] = __builtin_amdgcn_mfma_f32_16x16x32_bf16(ah, bl[i][kci], acc[i], 0, 0, 0);
      acc[i] = __builtin_amdgcn_mfma_f32_16x16x32_bf16(ah, bh[i][kci], acc[i], 0, 0, 0);
    }
  }
  int rbase = blockIdx.x * 16 + quad * 4;
#pragma unroll
  for (int r = 0; r < 4; ++r) {
    int row = rbase + r;
    if (row < N) {
      float dvr = dinv[row];
#pragma unroll
      for (int i = 0; i < NFW; ++i) {
        int nf = wv * NFW + i;
        Pout[(size_t)row * COUT + nf * 16 + mloc] = f2bf(acc[i][r] * dvr);
      }
    }
  }
}

// ---------------- final layer: R3-verified sliced staged aggregation + min-pool -----
__global__ __launch_bounds__(256) void k_agg_pool(const unsigned short* __restrict__ P,
                                                  const int* __restrict__ row_ptr,
                                                  const int* __restrict__ srcs,
                                                  const float* __restrict__ dinv,
                                                  const float* __restrict__ bias,
                                                  unsigned* __restrict__ minenc, int N) {
  const int CAP = 448;
  __shared__ int s_idx[4][CAP];
  __shared__ float s_red[4][32];
  int tid = threadIdx.x;
  int wv = tid >> 6, lane = tid & 63;
  int b8 = blockIdx.x & 7;
  int slice = b8 >> 2, part = b8 & 3;  // 2 slices x 4 parts
  int g0 = ((blockIdx.x >> 3) * 4 + part) * 64 + wv * 16;
  const char* Pb = (const char*)P + slice * 64;  // rows are 128B contiguous

  int i = lane >> 2, q = lane & 3;
  unsigned qoff = (unsigned)q * 16u;
  int d = g0 + i;
  int dc = d < N ? d : N - 1;
  bool valid = d < N;

  int e0 = row_ptr[g0 < N ? g0 : N];
  int e1 = row_ptr[(g0 + 16) < N ? (g0 + 16) : N];
  int lo_n = row_ptr[dc];
  int hi_n = row_ptr[valid ? d + 1 : dc];

  float a[8];
  {
    uint4 v = *(const uint4*)(Pb + ((unsigned)dc * 128u + qoff));
    a[0] = __uint_as_float(v.x << 16);
    a[1] = __uint_as_float(v.x & 0xffff0000u);
    a[2] = __uint_as_float(v.y << 16);
    a[3] = __uint_as_float(v.y & 0xffff0000u);
    a[4] = __uint_as_float(v.z << 16);
    a[5] = __uint_as_float(v.z & 0xffff0000u);
    a[6] = __uint_as_float(v.w << 16);
    a[7] = __uint_as_float(v.w & 0xffff0000u);
  }

  for (int w0 = e0; w0 < e1; w0 += CAP) {
    int wend = min(w0 + CAP, e1);
    int cnt = wend - w0;
    __builtin_amdgcn_wave_barrier();
    for (int t = lane; t < cnt; t += 64) s_idx[wv][t] = srcs[w0 + t];
    __builtin_amdgcn_wave_barrier();
    int j = max(lo_n, w0), hi = min(hi_n, wend);
    for (; j + 4 <= hi; j += 4) {
      unsigned i0 = (unsigned)s_idx[wv][j - w0];
      unsigned i1 = (unsigned)s_idx[wv][j - w0 + 1];
      unsigned i2 = (unsigned)s_idx[wv][j - w0 + 2];
      unsigned i3 = (unsigned)s_idx[wv][j - w0 + 3];
      uint4 v0 = *(const uint4*)(Pb + (i0 * 128u + qoff));
      uint4 v1 = *(const uint4*)(Pb + (i1 * 128u + qoff));
      uint4 v2 = *(const uint4*)(Pb + (i2 * 128u + qoff));
      uint4 v3 = *(const uint4*)(Pb + (i3 * 128u + qoff));
      acc8(a, v0);
      acc8(a, v1);
      acc8(a, v2);
      acc8(a, v3);
    }
    for (; j < hi; ++j) {
      unsigned i0 = (unsigned)s_idx[wv][j - w0];
      uint4 v0 = *(const uint4*)(Pb + (i0 * 128u + qoff));
      acc8(a, v0);
    }
  }

  int c0 = slice * 32 + q * 8;
  float dv = dinv[dc];
  float4 bv0 = *(const float4*)&bias[c0];
  float4 bv1 = *(const float4*)&bias[c0 + 4];
  float h[8];
  h[0] = dv * a[0] + bv0.x; h[1] = dv * a[1] + bv0.y;
  h[2] = dv * a[2] + bv0.z; h[3] = dv * a[3] + bv0.w;
  h[4] = dv * a[4] + bv1.x; h[5] = dv * a[5] + bv1.y;
  h[6] = dv * a[6] + bv1.z; h[7] = dv * a[7] + bv1.w;

  if (!valid) {
#pragma unroll
    for (int k = 0; k < 8; ++k) h[k] = FLT_MAX;
  }
#pragma unroll
  for (int off = 4; off < 64; off <<= 1) {
#pragma unroll
    for (int k = 0; k < 8; ++k) h[k] = fminf(h[k], __shfl_xor(h[k], off, 64));
  }
  if (lane < 4) {
#pragma unroll
    for (int k = 0; k < 8; ++k) s_red[wv][q * 8 + k] = h[k];
  }
  __syncthreads();
  if (tid < 32) {
    float mn = fminf(fminf(s_red[0][tid], s_red[1][tid]),
                     fminf(s_red[2][tid], s_red[3][tid]));
    atomicMin(&minenc[slice * 32 + tid], enc_min(mn));
  }
}

__global__ void k_decode(const unsigned* __restrict__ minenc, float* __restrict__ out) {
  int c = threadIdx.x;
  unsigned k = minenc[c];
  unsigned u = (k & 0x80000000u) ? (k & 0x7FFFFFFFu) : ~k;
  out[c] = __uint_as_float(u);
}

// ---------------- launch ----------------
extern "C" void kernel_launch(void* const* d_in, const int* in_sizes, int n_in,
                              void* d_out, int out_size, void* d_ws, size_t ws_size,
                              hipStream_t stream) {
  const float* X  = (const float*)d_in[0];
  const int* edge = (const int*)d_in[1];
  const float* W1 = (const float*)d_in[2];
  const float* b1 = (const float*)d_in[3];
  const float* W2 = (const float*)d_in[4];
  const float* b2 = (const float*)d_in[5];
  const float* W3 = (const float*)d_in[6];
  const float* b3 = (const float*)d_in[7];
  float* out = (float*)d_out;

  const int IN_CH = 128;
  int N = in_sizes[0] / IN_CH;
  int E = in_sizes[1] / 2;

  char* ws = (char*)d_ws;
  size_t off = 0;
  auto alloc = [&](size_t bytes) {
    void* p = ws + off;
    off = (off + bytes + 255) & ~(size_t)255;
    return p;
  };
  unsigned short* P1 = (unsigned short*)alloc((size_t)N * 128 * 2);  // 25.6 MB, 256B rows
  unsigned short* P2 = (unsigned short*)alloc((size_t)N * 128 * 2);  // 25.6 MB
  int* srcs      = (int*)alloc((size_t)E * 4);                       // 6.4 MB
  int* row_ptr   = (int*)alloc((size_t)(N + 1) * 4);
  float* dinv    = (float*)alloc((size_t)N * 4);
  int* bin_cur   = (int*)alloc((size_t)NB * 16 * 4);  // line-padded (stride 16 ints)
  unsigned* minenc = (unsigned*)alloc(256);
  unsigned short* w1h = (unsigned short*)alloc(16384 * 2);
  unsigned short* w1l = (unsigned short*)alloc(16384 * 2);
  unsigned short* w2h = (unsigned short*)alloc(16384 * 2);
  unsigned short* w2l = (unsigned short*)alloc(16384 * 2);
  unsigned short* w3h = (unsigned short*)alloc(8192 * 2);
  unsigned short* w3l = (unsigned short*)alloc(8192 * 2);

  // Aliases (lifetime-checked):
  //  pairs -> P2 region: written by k_bin_prep, read by k_buildB1 and
  //           k_scatter_gemm -- all strictly before k_agg_gemm<2> writes P2.
  //  P3    -> P1 region: P1 last read by k_agg_gemm<2>; k_agg_gemm<1> reads P2
  //           and writes P3.
  int binw = (N + NB - 1) / NB;              // 391 @ N=100K (<=512 LDS counters)
  int bcap = E / NB + 1024;                  // Poisson(6250), +1024 = 13 sigma
  int2* pairs = (int2*)P2;                   // NB*bcap*8B = 14.9 MB <= 25.6 MB
  unsigned short* P3 = P1;

  hipMemsetAsync(bin_cur, 0, (size_t)NB * 16 * 4, stream);
  hipMemsetAsync(minenc, 0xFF, 64 * 4, stream);  // encoded +max

  int gx = (N + 63) / 64;
  int nta = (E + 4095) / 4096;
  int gagg = (N + 15) / 16;
  int c64 = (N + 255) / 256;
  // front-end: fused bin+prepw -> buildB1 (row_ptr/dinv; self-computed bases)
  k_bin_prep<<<nta + 160, 256, 0, stream>>>(edge, E, bin_cur, pairs, binw, bcap, nta,
                                            W1, W2, W3, w1h, w1l, w2h, w2l, w3h, w3l);
  k_buildB1<<<NB, 256, 0, stream>>>(bin_cur, pairs, bcap, binw, N, E, row_ptr, dinv);
  // fused: LDS-cursor CSR scatter (first NB blocks) + gemm1 (X*W1 -> P1)
  k_scatter_gemm<<<NB + gx, 256, 0, stream>>>(X, w1h, w1l, dinv, P1, N,
                                              pairs, bin_cur, bcap, row_ptr, binw, N, srcs);
  // layer 1 agg + layer 2 gemm fused: P1 -> (H1) -> P2
  k_agg_gemm<2><<<gagg, 256, 0, stream>>>(P1, row_ptr, srcs, dinv, b1, w2h, w2l, P2, N);
  // layer 2 agg + layer 3 gemm fused: P2 -> (H2) -> P3
  k_agg_gemm<1><<<gagg, 256, 0, stream>>>(P2, row_ptr, srcs, dinv, b2, w3h, w3l, P3, N);
  // layer 3 agg + bias + min-pool (R3 staged variant)
  k_agg_pool<<<c64 * 8, 256, 0, stream>>>(P3, row_ptr, srcs, dinv, b3, minenc, N);
  // decode encoded mins -> out[64]
  k_decode<<<1, 64, 0, stream>>>(minenc, out);
}